// Round 5
// baseline (389.878 us; speedup 1.0000x reference)
//
#include <hip/hip_runtime.h>
#include <math.h>

// Problem constants
#define B_SZ 2
#define SEQ 512
#define DM 1024
#define DI 2048
#define DS 32
#define TOK (B_SZ*SEQ)        // 1024
#define NCH 8                 // scan chunks
#define CLEN (SEQ/NCH)        // 64
#define NG (CLEN/4)           // 16 groups of 4 steps
#define NPAIR (B_SZ*DI*16)    // 65536 (d, rope-pair) lanes

// fused weight layout (rows of K=1024, bf16):
//   [0,4096) W_in | [4096,6144) W_dt | [6144,6176) W_B | [6176,6208) W_C | [6208,6272) pad
#define NFUSED 6272

__device__ __forceinline__ unsigned short f2bf(float f) {
  unsigned int u = __builtin_bit_cast(unsigned int, f);
  unsigned int r = u + 0x7fffu + ((u >> 16) & 1u);   // RNE (inputs finite)
  return (unsigned short)(r >> 16);
}

// ---------------- fused fp32 -> bf16 cast of all 6 tensors, 8 elems/thread ----------------
__global__ __launch_bounds__(256) void fused_cast(const float* __restrict__ x,
                                                  const float* __restrict__ W_in,
                                                  const float* __restrict__ W_dt,
                                                  const float* __restrict__ W_B,
                                                  const float* __restrict__ W_C,
                                                  const float* __restrict__ W_out,
                                                  unsigned short* __restrict__ xb,
                                                  unsigned short* __restrict__ wcat,
                                                  unsigned short* __restrict__ wob) {
  int g = blockIdx.x * 256 + threadIdx.x;
  const float* s; unsigned short* dd; int off;
  if      (g <  131072) { s = x;     dd = xb;             off = 0; }
  else if (g <  655360) { s = W_in;  dd = wcat;           off = 131072; }
  else if (g <  917504) { s = W_dt;  dd = wcat + 4194304; off = 655360; }
  else if (g <  921600) { s = W_B;   dd = wcat + 6291456; off = 917504; }
  else if (g <  925696) { s = W_C;   dd = wcat + 6324224; off = 921600; }
  else if (g < 1187840) { s = W_out; dd = wob;            off = 925696; }
  else return;
  int i = g - off;
  float4 a = ((const float4*)s)[i * 2];
  float4 b = ((const float4*)s)[i * 2 + 1];
  union { unsigned short us[8]; uint4 v; } o;
  o.us[0] = f2bf(a.x); o.us[1] = f2bf(a.y); o.us[2] = f2bf(a.z); o.us[3] = f2bf(a.w);
  o.us[4] = f2bf(b.x); o.us[5] = f2bf(b.y); o.us[6] = f2bf(b.z); o.us[7] = f2bf(b.w);
  ((uint4*)dd)[i] = o.v;
}

// ---------------- bf16 MFMA GEMM (C = A * B^T), m97-style ----------------
typedef __attribute__((ext_vector_type(8))) short  frag8;
typedef __attribute__((ext_vector_type(4))) float  facc4;

__device__ __forceinline__ void gload_lds16(const unsigned short* g, unsigned short* l) {
  __builtin_amdgcn_global_load_lds((const __attribute__((address_space(1))) unsigned int*)g,
                                   (__attribute__((address_space(3))) unsigned int*)l, 16, 0, 0);
}

__device__ __forceinline__ float softplusf(float v) {
  return (v > 20.f) ? v : log1pf(expf(v));
}

// ROUTE=true epilogue (round-3 style scalar stores, token-major layouts):
//   n<2048 -> xs[m][n] | <4096 -> zb[m][n-2048] | <6144 -> dts[m][n-4096] (softplus+bias)
//   <6176 -> bcb[m][n-6144] | <6208 -> bcb[TOK*DS + m][n-6176] | else discard
template<int BMt, int BNt, bool ROUTE>
__global__ __launch_bounds__(256) void gemm_mfma(const unsigned short* __restrict__ A,
                                                 const unsigned short* __restrict__ Bw,
                                                 int K,
                                                 float* __restrict__ o_xs,
                                                 float* __restrict__ o_zb,
                                                 float* __restrict__ o_dts,
                                                 float* __restrict__ o_bcb,
                                                 const float* __restrict__ b_dt,
                                                 const float* __restrict__ dt_bias,
                                                 float* __restrict__ o_c, int ldc) {
  constexpr int FM = BMt / 32, FN = BNt / 32;
  constexpr int IA = BMt / 64, IB = BNt / 64;
  __shared__ __align__(16) unsigned short As[BMt * 32];
  __shared__ __align__(16) unsigned short Bs[BNt * 32];
  const int tid = threadIdx.x;
  const int w = tid >> 6, lane = tid & 63;
  const int wm = w >> 1, wn = w & 1;
  const int m0 = blockIdx.y * BMt, n0 = blockIdx.x * BNt;
  const int r = lane & 15, q = lane >> 4;
  const int grow = lane >> 2, gk = (lane & 3) * 8;
  facc4 acc[FM][FN] = {};
  const unsigned short* Ag = A + (size_t)m0 * K + gk;
  const unsigned short* Bg = Bw + (size_t)n0 * K + gk;

  for (int k0 = 0; k0 < K; k0 += 32) {
#pragma unroll
    for (int i = 0; i < IA; ++i) {
      int ch = i * 4 + w;
      gload_lds16(Ag + (size_t)(ch * 16 + grow) * K + k0, &As[ch * 512]);
    }
#pragma unroll
    for (int i = 0; i < IB; ++i) {
      int ch = i * 4 + w;
      gload_lds16(Bg + (size_t)(ch * 16 + grow) * K + k0, &Bs[ch * 512]);
    }
    __syncthreads();
    frag8 af[FM], bf[FN];
#pragma unroll
    for (int i = 0; i < FM; ++i)
      af[i] = *(const frag8*)&As[(wm * (BMt / 2) + i * 16 + r) * 32 + q * 8];
#pragma unroll
    for (int jj = 0; jj < FN; ++jj)
      bf[jj] = *(const frag8*)&Bs[(wn * (BNt / 2) + jj * 16 + r) * 32 + q * 8];
#pragma unroll
    for (int i = 0; i < FM; ++i)
#pragma unroll
      for (int jj = 0; jj < FN; ++jj)
        acc[i][jj] = __builtin_amdgcn_mfma_f32_16x16x32_bf16(af[i], bf[jj], acc[i][jj], 0, 0, 0);
    __syncthreads();
  }

#pragma unroll
  for (int i = 0; i < FM; ++i) {
#pragma unroll
    for (int jj = 0; jj < FN; ++jj) {
      int n = n0 + wn * (BNt / 2) + jj * 16 + r;
      int mb = m0 + wm * (BMt / 2) + i * 16 + q * 4;
      if (ROUTE) {
        if (n < 2048) {
#pragma unroll
          for (int rg = 0; rg < 4; ++rg)
            o_xs[(size_t)(mb + rg) * DI + n] = acc[i][jj][rg];
        } else if (n < 4096) {
#pragma unroll
          for (int rg = 0; rg < 4; ++rg)
            o_zb[(size_t)(mb + rg) * DI + (n - 2048)] = acc[i][jj][rg];
        } else if (n < 6144) {
          int d = n - 4096;
          float bias = b_dt[d] + dt_bias[d];
#pragma unroll
          for (int rg = 0; rg < 4; ++rg)
            o_dts[(size_t)(mb + rg) * DI + d] = softplusf(acc[i][jj][rg] + bias);
        } else if (n < 6176) {
#pragma unroll
          for (int rg = 0; rg < 4; ++rg)
            o_bcb[(size_t)(mb + rg) * DS + (n - 6144)] = acc[i][jj][rg];
        } else if (n < 6208) {
#pragma unroll
          for (int rg = 0; rg < 4; ++rg)
            o_bcb[(size_t)TOK * DS + (size_t)(mb + rg) * DS + (n - 6176)] = acc[i][jj][rg];
        }
      } else {
#pragma unroll
        for (int rg = 0; rg < 4; ++rg)
          o_c[(size_t)(mb + rg) * ldc + n] = acc[i][jj][rg];
      }
    }
  }
}

// ---------------- chunked scan: round-3 coalesced/broadcast layouts + 4-step group prefetch ---
__global__ __launch_bounds__(256) void scan_p1(const float* __restrict__ xs,
                                               const float* __restrict__ dts,
                                               const float* __restrict__ bcb,
                                               const float* __restrict__ A_log,
                                               const float* __restrict__ rope,
                                               float* __restrict__ Pbuf) {
  const int blk = blockIdx.x;
  const int c = blk >> 8;
  const int sub = blk & 255;
  const int b = sub >> 7;
  const int dbase = (sub & 127) << 4;
  const int dl = threadIdx.x >> 4;
  const int j = threadIdx.x & 15;
  const int d = dbase + dl;
  const int l0 = c * CLEN;

  const float Ar_h = -0.5f * expf(A_log[d * DS + j]);
  const float Ai_h = -0.5f * expf(A_log[d * DS + j + 16]);
  const float fr = rope[j];
  float sn, cs, sF, cF;
  sincosf((float)l0 * fr, &sn, &cs);
  sincosf(fr, &sF, &cF);

  const size_t base = (size_t)(b * SEQ + l0);
  const float* dtp = dts + base * DI + d;
  const float* xp  = xs  + base * DI + d;
  const float* Brp = bcb + base * DS + j;
  const float* Bip = Brp + 16;

  float p00 = 1.f, p01 = 0.f, p10 = 0.f, p11 = 1.f;
  float ur = 0.f, ui = 0.f;

  float cdt[4], cx[4], cbr[4], cbi[4];
#pragma unroll
  for (int t = 0; t < 4; ++t) {
    cdt[t] = dtp[t * DI]; cx[t] = xp[t * DI];
    cbr[t] = Brp[t * DS]; cbi[t] = Bip[t * DS];
  }

  for (int g = 0; g < NG; ++g) {
    const int gb = ((g + 1 < NG) ? g + 1 : g) * 4;
    float ndt[4], nx[4], nbr[4], nbi[4];
#pragma unroll
    for (int t = 0; t < 4; ++t) {
      ndt[t] = dtp[(gb + t) * DI]; nx[t] = xp[(gb + t) * DI];
      nbr[t] = Brp[(gb + t) * DS]; nbi[t] = Bip[(gb + t) * DS];
    }
#pragma unroll
    for (int t = 0; t < 4; ++t) {
      float dtd = cdt[t], xin = cx[t], Br = cbr[t], Bi = cbi[t];
      float hr = dtd * Ar_h, hi = dtd * Ai_h;
      float invr = __fdividef(1.f, 1.f - hr);
      float invi = __fdividef(1.f, 1.f - hi);
      float Abr = (1.f + hr) * invr;
      float Abi = (1.f + hi) * invi;
      float dx = dtd * xin;
      float bxr = dx * invr * Br;
      float bxi = dx * invi * Bi;
      float tr = fmaf(Abr, ur, bxr);
      float ti = fmaf(Abi, ui, bxi);
      ur = tr * cs - ti * sn;
      ui = tr * sn + ti * cs;
      float q00 = Abr * p00, q01 = Abr * p01;
      float q10 = Abi * p10, q11 = Abi * p11;
      p00 = q00 * cs - q10 * sn; p10 = q00 * sn + q10 * cs;
      p01 = q01 * cs - q11 * sn; p11 = q01 * sn + q11 * cs;
      float nc = fmaf(cs, cF, -sn * sF);
      float ns = fmaf(sn, cF,  cs * sF);
      cs = nc; sn = ns;
    }
#pragma unroll
    for (int t = 0; t < 4; ++t) {
      cdt[t] = ndt[t]; cx[t] = nx[t]; cbr[t] = nbr[t]; cbi[t] = nbi[t];
    }
  }
  const int pair = (b * DI + d) * 16 + j;
  Pbuf[(c * 6 + 0) * NPAIR + pair] = p00;
  Pbuf[(c * 6 + 1) * NPAIR + pair] = p01;
  Pbuf[(c * 6 + 2) * NPAIR + pair] = p10;
  Pbuf[(c * 6 + 3) * NPAIR + pair] = p11;
  Pbuf[(c * 6 + 4) * NPAIR + pair] = ur;
  Pbuf[(c * 6 + 5) * NPAIR + pair] = ui;
}

__global__ __launch_bounds__(256) void scan_p2(const float* __restrict__ Pbuf,
                                               float* __restrict__ Sbuf) {
  int pair = blockIdx.x * 256 + threadIdx.x;
  float sr = 0.f, si = 0.f;
#pragma unroll
  for (int c = 0; c < NCH; ++c) {
    Sbuf[(c * 2 + 0) * NPAIR + pair] = sr;
    Sbuf[(c * 2 + 1) * NPAIR + pair] = si;
    float p00 = Pbuf[(c * 6 + 0) * NPAIR + pair];
    float p01 = Pbuf[(c * 6 + 1) * NPAIR + pair];
    float p10 = Pbuf[(c * 6 + 2) * NPAIR + pair];
    float p11 = Pbuf[(c * 6 + 3) * NPAIR + pair];
    float ur  = Pbuf[(c * 6 + 4) * NPAIR + pair];
    float ui  = Pbuf[(c * 6 + 5) * NPAIR + pair];
    float nr = p00 * sr + p01 * si + ur;
    float ni = p10 * sr + p11 * si + ui;
    sr = nr; si = ni;
  }
}

__global__ __launch_bounds__(256) void scan_p3(const float* __restrict__ xs,
                                               const float* __restrict__ dts,
                                               const float* __restrict__ bcb,
                                               const float* __restrict__ A_log,
                                               const float* __restrict__ rope,
                                               const float* __restrict__ Sbuf,
                                               float* __restrict__ y,
                                               float* __restrict__ fstate) {
  const int blk = blockIdx.x;
  const int c = blk >> 8;
  const int sub = blk & 255;
  const int b = sub >> 7;
  const int dbase = (sub & 127) << 4;
  const int dl = threadIdx.x >> 4;
  const int j = threadIdx.x & 15;
  const int d = dbase + dl;
  const int l0 = c * CLEN;

  const float Ar_h = -0.5f * expf(A_log[d * DS + j]);
  const float Ai_h = -0.5f * expf(A_log[d * DS + j + 16]);
  const float fr = rope[j];
  float sn, cs, sF, cF;
  sincosf((float)l0 * fr, &sn, &cs);
  sincosf(fr, &sF, &cF);

  const size_t base = (size_t)(b * SEQ + l0);
  const float* dtp = dts + base * DI + d;
  const float* xp  = xs  + base * DI + d;
  const float* Brp = bcb + base * DS + j;
  const float* Bip = Brp + 16;
  const float* Crp = bcb + (size_t)TOK * DS + base * DS + j;
  const float* Cip = Crp + 16;
  float* yp = y + base * DI + d;

  const int pair = (b * DI + d) * 16 + j;
  float sr = Sbuf[(c * 2 + 0) * NPAIR + pair];
  float si = Sbuf[(c * 2 + 1) * NPAIR + pair];

  float cdt[4], cx[4], cbr[4], cbi[4], ccr[4], cci[4];
#pragma unroll
  for (int t = 0; t < 4; ++t) {
    cdt[t] = dtp[t * DI]; cx[t] = xp[t * DI];
    cbr[t] = Brp[t * DS]; cbi[t] = Bip[t * DS];
    ccr[t] = Crp[t * DS]; cci[t] = Cip[t * DS];
  }

  for (int g = 0; g < NG; ++g) {
    const int gb = ((g + 1 < NG) ? g + 1 : g) * 4;
    float ndt[4], nx[4], nbr[4], nbi[4], ncr[4], nci[4];
#pragma unroll
    for (int t = 0; t < 4; ++t) {
      ndt[t] = dtp[(gb + t) * DI]; nx[t] = xp[(gb + t) * DI];
      nbr[t] = Brp[(gb + t) * DS]; nbi[t] = Bip[(gb + t) * DS];
      ncr[t] = Crp[(gb + t) * DS]; nci[t] = Cip[(gb + t) * DS];
    }
#pragma unroll
    for (int t = 0; t < 4; ++t) {
      float dtd = cdt[t], xin = cx[t], Br = cbr[t], Bi = cbi[t];
      float hr = dtd * Ar_h, hi = dtd * Ai_h;
      float invr = __fdividef(1.f, 1.f - hr);
      float invi = __fdividef(1.f, 1.f - hi);
      float Abr = (1.f + hr) * invr;
      float Abi = (1.f + hi) * invi;
      float dx = dtd * xin;
      float bxr = dx * invr * Br;
      float bxi = dx * invi * Bi;
      float tr = fmaf(Abr, sr, bxr);
      float ti = fmaf(Abi, si, bxi);
      sr = tr * cs - ti * sn;
      si = tr * sn + ti * cs;
      float p = sr * ccr[t] + si * cci[t];
      p += __shfl_xor(p, 8);
      p += __shfl_xor(p, 4);
      p += __shfl_xor(p, 2);
      p += __shfl_xor(p, 1);
      if (j == 0) yp[(g * 4 + t) * DI] = p;
      float nc = fmaf(cs, cF, -sn * sF);
      float ns = fmaf(sn, cF,  cs * sF);
      cs = nc; sn = ns;
    }
#pragma unroll
    for (int t = 0; t < 4; ++t) {
      cdt[t] = ndt[t]; cx[t] = nx[t]; cbr[t] = nbr[t]; cbi[t] = nbi[t];
      ccr[t] = ncr[t]; cci[t] = nci[t];
    }
  }
  if (c == NCH - 1) {
    fstate[((size_t)b * DI + d) * DS + j]      = sr;
    fstate[((size_t)b * DI + d) * DS + j + 16] = si;
  }
}

// ---------------- gate (y * silu(z)) + LayerNorm, bf16 output ----------------
__global__ __launch_bounds__(256) void gate_ln(const float* __restrict__ y,
                                               const float* __restrict__ zb,
                                               const float* __restrict__ lw,
                                               const float* __restrict__ lb,
                                               unsigned short* __restrict__ o) {
  int tok = blockIdx.x;
  int t = threadIdx.x;
  float g[8];
  float sum = 0.f, sq = 0.f;
#pragma unroll
  for (int i = 0; i < 8; ++i) {
    int dd = t + i * 256;
    float yv = y[(size_t)tok * DI + dd];
    float zv = zb[(size_t)tok * DI + dd];
    float sg = zv / (1.f + expf(-zv));
    float v = yv * sg;
    g[i] = v; sum += v; sq += v * v;
  }
#pragma unroll
  for (int off = 32; off; off >>= 1) { sum += __shfl_xor(sum, off); sq += __shfl_xor(sq, off); }
  __shared__ float rs[4], rq[4];
  int w = t >> 6;
  if ((t & 63) == 0) { rs[w] = sum; rq[w] = sq; }
  __syncthreads();
  sum = rs[0] + rs[1] + rs[2] + rs[3];
  sq  = rq[0] + rq[1] + rq[2] + rq[3];
  float mu = sum * (1.f / DI);
  float var = sq * (1.f / DI) - mu * mu;
  float rstd = rsqrtf(var + 1e-5f);
#pragma unroll
  for (int i = 0; i < 8; ++i) {
    int dd = t + i * 256;
    o[(size_t)tok * DI + dd] = f2bf((g[i] - mu) * rstd * lw[dd] + lb[dd]);
  }
}

// ---------------- launch ----------------
extern "C" void kernel_launch(void* const* d_in, const int* in_sizes, int n_in,
                              void* d_out, int out_size, void* d_ws, size_t ws_size,
                              hipStream_t stream) {
  const float* x       = (const float*)d_in[0];
  const float* W_in    = (const float*)d_in[1];
  const float* A_log   = (const float*)d_in[2];
  const float* W_B     = (const float*)d_in[3];
  const float* W_C     = (const float*)d_in[4];
  const float* W_dt    = (const float*)d_in[5];
  const float* b_dt    = (const float*)d_in[6];
  const float* dt_bias = (const float*)d_in[7];
  const float* rope    = (const float*)d_in[8];
  const float* ln_w    = (const float*)d_in[9];
  const float* ln_b    = (const float*)d_in[10];
  const float* W_out   = (const float*)d_in[11];
  float* out = (float*)d_out;
  float* ws = (float*)d_ws;

  // workspace layout (float offsets); overlays noted. Max = 12,189,696 f = 48.8 MB (proven R3)
  float* xs   = ws;                                   // [0, 2097152)
  float* zb   = ws + 2097152;                         // [2097152, 4194304)
  float* dts  = ws + 4194304;                         // [4194304, 6291456)
  float* bcb  = ws + 6291456;                         // [6291456, 6356992)
  unsigned short* wob  = (unsigned short*)(ws + 6356992);  // 2M bf16   [.., 7405568)
  unsigned short* xb   = (unsigned short*)(ws + 7405568);  // 1M bf16   [.., 7929856)
  unsigned short* wcat = (unsigned short*)(ws + 7929856);  // 6.42M bf16 [.., 11141120)
  float* Pbuf = ws + 7929856;                         // 3145728 f, alias wcat (dead after GEMM)
  float* Sbuf = ws + 11141120;                        // 1048576 f  [.., 12189696)
  float* yb   = ws + 7929856;                         // 2097152 f, alias Pbuf (dead after p2)
  unsigned short* lnb = (unsigned short*)(ws + 10027008);  // 2M bf16, dead Pbuf tail
  float* fstate = out + (size_t)TOK * DM;

  // 1) fused bf16 casts (x, W_in, W_dt, W_B, W_C, W_out)
  fused_cast<<<4640, 256, 0, stream>>>(x, W_in, W_dt, W_B, W_C, W_out, xb, wcat, wob);
  // 2) fused input GEMM: routes to xs / zb / dts(softplus) / bcb (token-major, coalesced for scan)
  gemm_mfma<128, 128, true><<<dim3(NFUSED / 128, TOK / 128), 256, 0, stream>>>(
      xb, wcat, DM, xs, zb, dts, bcb, b_dt, dt_bias, nullptr, 0);
  // 3) chunked scan with 4-step register-group prefetch
  scan_p1<<<NCH * 256, 256, 0, stream>>>(xs, dts, bcb, A_log, rope, Pbuf);
  scan_p2<<<NPAIR / 256, 256, 0, stream>>>(Pbuf, Sbuf);
  scan_p3<<<NCH * 256, 256, 0, stream>>>(xs, dts, bcb, A_log, rope, Sbuf, yb, fstate);
  // 4) gate + LN (bf16 out)
  gate_ln<<<TOK, 256, 0, stream>>>(yb, zb, ln_w, ln_b, lnb);
  // 5) out = ln @ W_out^T
  gemm_mfma<64, 64, false><<<dim3(DM / 64, TOK / 64), 256, 0, stream>>>(
      lnb, wob, DI, nullptr, nullptr, nullptr, nullptr, nullptr, nullptr, out, DM);
}

// Round 6
// 274.193 us; speedup vs baseline: 1.4219x; 1.4219x over previous
//
#include <hip/hip_runtime.h>
#include <math.h>

// Problem constants
#define B_SZ 2
#define SEQ 512
#define DM 1024
#define DI 2048
#define DS 32
#define TOK (B_SZ*SEQ)        // 1024
#define NCH 8                 // scan chunks
#define CLEN (SEQ/NCH)        // 64
#define NG (CLEN/4)           // 16 groups of 4 steps
#define NPAIR (B_SZ*DI*16)    // 65536 (d, rope-pair) lanes

// fused weight layout (rows of K=1024, bf16):
//   [0,4096) W_in | [4096,6144) W_dt | [6144,6176) W_B | [6176,6208) W_C | [6208,6272) pad
#define NFUSED 6272

__device__ __forceinline__ unsigned short f2bf(float f) {
  unsigned int u = __builtin_bit_cast(unsigned int, f);
  unsigned int r = u + 0x7fffu + ((u >> 16) & 1u);   // RNE (inputs finite)
  return (unsigned short)(r >> 16);
}

// ---------------- fused fp32 -> bf16 cast of all 6 tensors, 8 elems/thread ----------------
__global__ __launch_bounds__(256) void fused_cast(const float* __restrict__ x,
                                                  const float* __restrict__ W_in,
                                                  const float* __restrict__ W_dt,
                                                  const float* __restrict__ W_B,
                                                  const float* __restrict__ W_C,
                                                  const float* __restrict__ W_out,
                                                  unsigned short* __restrict__ xb,
                                                  unsigned short* __restrict__ wcat,
                                                  unsigned short* __restrict__ wob) {
  int g = blockIdx.x * 256 + threadIdx.x;
  const float* s; unsigned short* dd; int off;
  if      (g <  131072) { s = x;     dd = xb;             off = 0; }
  else if (g <  655360) { s = W_in;  dd = wcat;           off = 131072; }
  else if (g <  917504) { s = W_dt;  dd = wcat + 4194304; off = 655360; }
  else if (g <  921600) { s = W_B;   dd = wcat + 6291456; off = 917504; }
  else if (g <  925696) { s = W_C;   dd = wcat + 6324224; off = 921600; }
  else if (g < 1187840) { s = W_out; dd = wob;            off = 925696; }
  else return;
  int i = g - off;
  float4 a = ((const float4*)s)[i * 2];
  float4 b = ((const float4*)s)[i * 2 + 1];
  union { unsigned short us[8]; uint4 v; } o;
  o.us[0] = f2bf(a.x); o.us[1] = f2bf(a.y); o.us[2] = f2bf(a.z); o.us[3] = f2bf(a.w);
  o.us[4] = f2bf(b.x); o.us[5] = f2bf(b.y); o.us[6] = f2bf(b.z); o.us[7] = f2bf(b.w);
  ((uint4*)dd)[i] = o.v;
}

// ---------------- bf16 MFMA GEMM (C = A * B^T) ----------------
typedef __attribute__((ext_vector_type(8))) short  frag8;
typedef __attribute__((ext_vector_type(4))) float  facc4;

__device__ __forceinline__ void gload_lds16(const unsigned short* g, unsigned short* l) {
  __builtin_amdgcn_global_load_lds((const __attribute__((address_space(1))) unsigned int*)g,
                                   (__attribute__((address_space(3))) unsigned int*)l, 16, 0, 0);
}

__device__ __forceinline__ float softplus_fast(float v) {
  // max(v,0) + log(1+exp(-|v|)), intrinsic-only, branch-free; abs err ~1e-7
  return fmaxf(v, 0.f) + __logf(1.f + __expf(-fabsf(v)));
}

// 1-D grid, XCD-swizzled: xcd = bid&7 gets contiguous n-tile slice (B fits per-XCD L2).
// MT = number of m-tiles (m fast axis within an XCD's slice).
template<int BMt, int BNt, int MT, bool ROUTE>
__global__ __launch_bounds__(256) void gemm_mfma(const unsigned short* __restrict__ A,
                                                 const unsigned short* __restrict__ Bw,
                                                 int K,
                                                 float* __restrict__ o_xs,
                                                 float* __restrict__ o_zb,
                                                 float* __restrict__ o_dts,
                                                 float* __restrict__ o_bcb,
                                                 const float* __restrict__ b_dt,
                                                 const float* __restrict__ dt_bias,
                                                 float* __restrict__ o_c, int ldc) {
  constexpr int FM = BMt / 32, FN = BNt / 32;
  constexpr int IA = BMt / 64, IB = BNt / 64;
  __shared__ __align__(16) unsigned short As[BMt * 32];
  __shared__ __align__(16) unsigned short Bs[BNt * 32];
  const int tid = threadIdx.x;
  const int w = tid >> 6, lane = tid & 63;
  const int wm = w >> 1, wn = w & 1;
  // XCD swizzle: round-robin dispatch assumed; each xcd works a contiguous W range
  const int bid = blockIdx.x;
  const int Wk = (bid & 7) * ((int)gridDim.x >> 3) + (bid >> 3);
  const int m0 = (Wk % MT) * BMt;
  const int n0 = (Wk / MT) * BNt;
  const int r = lane & 15, q = lane >> 4;
  const int grow = lane >> 2, gk = (lane & 3) * 8;
  facc4 acc[FM][FN] = {};
  const unsigned short* Ag = A + (size_t)m0 * K + gk;
  const unsigned short* Bg = Bw + (size_t)n0 * K + gk;

  for (int k0 = 0; k0 < K; k0 += 32) {
#pragma unroll
    for (int i = 0; i < IA; ++i) {
      int ch = i * 4 + w;
      gload_lds16(Ag + (size_t)(ch * 16 + grow) * K + k0, &As[ch * 512]);
    }
#pragma unroll
    for (int i = 0; i < IB; ++i) {
      int ch = i * 4 + w;
      gload_lds16(Bg + (size_t)(ch * 16 + grow) * K + k0, &Bs[ch * 512]);
    }
    __syncthreads();
    frag8 af[FM], bf[FN];
#pragma unroll
    for (int i = 0; i < FM; ++i)
      af[i] = *(const frag8*)&As[(wm * (BMt / 2) + i * 16 + r) * 32 + q * 8];
#pragma unroll
    for (int jj = 0; jj < FN; ++jj)
      bf[jj] = *(const frag8*)&Bs[(wn * (BNt / 2) + jj * 16 + r) * 32 + q * 8];
#pragma unroll
    for (int i = 0; i < FM; ++i)
#pragma unroll
      for (int jj = 0; jj < FN; ++jj)
        acc[i][jj] = __builtin_amdgcn_mfma_f32_16x16x32_bf16(af[i], bf[jj], acc[i][jj], 0, 0, 0);
    __syncthreads();
  }

#pragma unroll
  for (int i = 0; i < FM; ++i) {
#pragma unroll
    for (int jj = 0; jj < FN; ++jj) {
      int n = n0 + wn * (BNt / 2) + jj * 16 + r;
      int mb = m0 + wm * (BMt / 2) + i * 16 + q * 4;
      if (ROUTE) {
        if (n < 2048) {
#pragma unroll
          for (int rg = 0; rg < 4; ++rg)
            o_xs[(size_t)(mb + rg) * DI + n] = acc[i][jj][rg];
        } else if (n < 4096) {
#pragma unroll
          for (int rg = 0; rg < 4; ++rg)
            o_zb[(size_t)(mb + rg) * DI + (n - 2048)] = acc[i][jj][rg];
        } else if (n < 6144) {
          int d = n - 4096;
          float bias = b_dt[d] + dt_bias[d];
#pragma unroll
          for (int rg = 0; rg < 4; ++rg)
            o_dts[(size_t)(mb + rg) * DI + d] = softplus_fast(acc[i][jj][rg] + bias);
        } else if (n < 6176) {
#pragma unroll
          for (int rg = 0; rg < 4; ++rg)
            o_bcb[(size_t)(mb + rg) * DS + (n - 6144)] = acc[i][jj][rg];
        } else if (n < 6208) {
#pragma unroll
          for (int rg = 0; rg < 4; ++rg)
            o_bcb[(size_t)TOK * DS + (size_t)(mb + rg) * DS + (n - 6176)] = acc[i][jj][rg];
        }
      } else {
#pragma unroll
        for (int rg = 0; rg < 4; ++rg)
          o_c[(size_t)(mb + rg) * ldc + n] = acc[i][jj][rg];
      }
    }
  }
}

// ---------------- chunked scan (unchanged from R5: coalesced + 4-step prefetch) ----------------
__global__ __launch_bounds__(256) void scan_p1(const float* __restrict__ xs,
                                               const float* __restrict__ dts,
                                               const float* __restrict__ bcb,
                                               const float* __restrict__ A_log,
                                               const float* __restrict__ rope,
                                               float* __restrict__ Pbuf) {
  const int blk = blockIdx.x;
  const int c = blk >> 8;
  const int sub = blk & 255;
  const int b = sub >> 7;
  const int dbase = (sub & 127) << 4;
  const int dl = threadIdx.x >> 4;
  const int j = threadIdx.x & 15;
  const int d = dbase + dl;
  const int l0 = c * CLEN;

  const float Ar_h = -0.5f * expf(A_log[d * DS + j]);
  const float Ai_h = -0.5f * expf(A_log[d * DS + j + 16]);
  const float fr = rope[j];
  float sn, cs, sF, cF;
  sincosf((float)l0 * fr, &sn, &cs);
  sincosf(fr, &sF, &cF);

  const size_t base = (size_t)(b * SEQ + l0);
  const float* dtp = dts + base * DI + d;
  const float* xp  = xs  + base * DI + d;
  const float* Brp = bcb + base * DS + j;
  const float* Bip = Brp + 16;

  float p00 = 1.f, p01 = 0.f, p10 = 0.f, p11 = 1.f;
  float ur = 0.f, ui = 0.f;

  float cdt[4], cx[4], cbr[4], cbi[4];
#pragma unroll
  for (int t = 0; t < 4; ++t) {
    cdt[t] = dtp[t * DI]; cx[t] = xp[t * DI];
    cbr[t] = Brp[t * DS]; cbi[t] = Bip[t * DS];
  }

  for (int g = 0; g < NG; ++g) {
    const int gb = ((g + 1 < NG) ? g + 1 : g) * 4;
    float ndt[4], nx[4], nbr[4], nbi[4];
#pragma unroll
    for (int t = 0; t < 4; ++t) {
      ndt[t] = dtp[(gb + t) * DI]; nx[t] = xp[(gb + t) * DI];
      nbr[t] = Brp[(gb + t) * DS]; nbi[t] = Bip[(gb + t) * DS];
    }
#pragma unroll
    for (int t = 0; t < 4; ++t) {
      float dtd = cdt[t], xin = cx[t], Br = cbr[t], Bi = cbi[t];
      float hr = dtd * Ar_h, hi = dtd * Ai_h;
      float invr = __fdividef(1.f, 1.f - hr);
      float invi = __fdividef(1.f, 1.f - hi);
      float Abr = (1.f + hr) * invr;
      float Abi = (1.f + hi) * invi;
      float dx = dtd * xin;
      float bxr = dx * invr * Br;
      float bxi = dx * invi * Bi;
      float tr = fmaf(Abr, ur, bxr);
      float ti = fmaf(Abi, ui, bxi);
      ur = tr * cs - ti * sn;
      ui = tr * sn + ti * cs;
      float q00 = Abr * p00, q01 = Abr * p01;
      float q10 = Abi * p10, q11 = Abi * p11;
      p00 = q00 * cs - q10 * sn; p10 = q00 * sn + q10 * cs;
      p01 = q01 * cs - q11 * sn; p11 = q01 * sn + q11 * cs;
      float nc = fmaf(cs, cF, -sn * sF);
      float ns = fmaf(sn, cF,  cs * sF);
      cs = nc; sn = ns;
    }
#pragma unroll
    for (int t = 0; t < 4; ++t) {
      cdt[t] = ndt[t]; cx[t] = nx[t]; cbr[t] = nbr[t]; cbi[t] = nbi[t];
    }
  }
  const int pair = (b * DI + d) * 16 + j;
  Pbuf[(c * 6 + 0) * NPAIR + pair] = p00;
  Pbuf[(c * 6 + 1) * NPAIR + pair] = p01;
  Pbuf[(c * 6 + 2) * NPAIR + pair] = p10;
  Pbuf[(c * 6 + 3) * NPAIR + pair] = p11;
  Pbuf[(c * 6 + 4) * NPAIR + pair] = ur;
  Pbuf[(c * 6 + 5) * NPAIR + pair] = ui;
}

__global__ __launch_bounds__(256) void scan_p2(const float* __restrict__ Pbuf,
                                               float* __restrict__ Sbuf) {
  int pair = blockIdx.x * 256 + threadIdx.x;
  float sr = 0.f, si = 0.f;
#pragma unroll
  for (int c = 0; c < NCH; ++c) {
    Sbuf[(c * 2 + 0) * NPAIR + pair] = sr;
    Sbuf[(c * 2 + 1) * NPAIR + pair] = si;
    float p00 = Pbuf[(c * 6 + 0) * NPAIR + pair];
    float p01 = Pbuf[(c * 6 + 1) * NPAIR + pair];
    float p10 = Pbuf[(c * 6 + 2) * NPAIR + pair];
    float p11 = Pbuf[(c * 6 + 3) * NPAIR + pair];
    float ur  = Pbuf[(c * 6 + 4) * NPAIR + pair];
    float ui  = Pbuf[(c * 6 + 5) * NPAIR + pair];
    float nr = p00 * sr + p01 * si + ur;
    float ni = p10 * sr + p11 * si + ui;
    sr = nr; si = ni;
  }
}

__global__ __launch_bounds__(256) void scan_p3(const float* __restrict__ xs,
                                               const float* __restrict__ dts,
                                               const float* __restrict__ bcb,
                                               const float* __restrict__ A_log,
                                               const float* __restrict__ rope,
                                               const float* __restrict__ Sbuf,
                                               float* __restrict__ y,
                                               float* __restrict__ fstate) {
  const int blk = blockIdx.x;
  const int c = blk >> 8;
  const int sub = blk & 255;
  const int b = sub >> 7;
  const int dbase = (sub & 127) << 4;
  const int dl = threadIdx.x >> 4;
  const int j = threadIdx.x & 15;
  const int d = dbase + dl;
  const int l0 = c * CLEN;

  const float Ar_h = -0.5f * expf(A_log[d * DS + j]);
  const float Ai_h = -0.5f * expf(A_log[d * DS + j + 16]);
  const float fr = rope[j];
  float sn, cs, sF, cF;
  sincosf((float)l0 * fr, &sn, &cs);
  sincosf(fr, &sF, &cF);

  const size_t base = (size_t)(b * SEQ + l0);
  const float* dtp = dts + base * DI + d;
  const float* xp  = xs  + base * DI + d;
  const float* Brp = bcb + base * DS + j;
  const float* Bip = Brp + 16;
  const float* Crp = bcb + (size_t)TOK * DS + base * DS + j;
  const float* Cip = Crp + 16;
  float* yp = y + base * DI + d;

  const int pair = (b * DI + d) * 16 + j;
  float sr = Sbuf[(c * 2 + 0) * NPAIR + pair];
  float si = Sbuf[(c * 2 + 1) * NPAIR + pair];

  float cdt[4], cx[4], cbr[4], cbi[4], ccr[4], cci[4];
#pragma unroll
  for (int t = 0; t < 4; ++t) {
    cdt[t] = dtp[t * DI]; cx[t] = xp[t * DI];
    cbr[t] = Brp[t * DS]; cbi[t] = Bip[t * DS];
    ccr[t] = Crp[t * DS]; cci[t] = Cip[t * DS];
  }

  for (int g = 0; g < NG; ++g) {
    const int gb = ((g + 1 < NG) ? g + 1 : g) * 4;
    float ndt[4], nx[4], nbr[4], nbi[4], ncr[4], nci[4];
#pragma unroll
    for (int t = 0; t < 4; ++t) {
      ndt[t] = dtp[(gb + t) * DI]; nx[t] = xp[(gb + t) * DI];
      nbr[t] = Brp[(gb + t) * DS]; nbi[t] = Bip[(gb + t) * DS];
      ncr[t] = Crp[(gb + t) * DS]; nci[t] = Cip[(gb + t) * DS];
    }
#pragma unroll
    for (int t = 0; t < 4; ++t) {
      float dtd = cdt[t], xin = cx[t], Br = cbr[t], Bi = cbi[t];
      float hr = dtd * Ar_h, hi = dtd * Ai_h;
      float invr = __fdividef(1.f, 1.f - hr);
      float invi = __fdividef(1.f, 1.f - hi);
      float Abr = (1.f + hr) * invr;
      float Abi = (1.f + hi) * invi;
      float dx = dtd * xin;
      float bxr = dx * invr * Br;
      float bxi = dx * invi * Bi;
      float tr = fmaf(Abr, sr, bxr);
      float ti = fmaf(Abi, si, bxi);
      sr = tr * cs - ti * sn;
      si = tr * sn + ti * cs;
      float p = sr * ccr[t] + si * cci[t];
      p += __shfl_xor(p, 8);
      p += __shfl_xor(p, 4);
      p += __shfl_xor(p, 2);
      p += __shfl_xor(p, 1);
      if (j == 0) yp[(g * 4 + t) * DI] = p;
      float nc = fmaf(cs, cF, -sn * sF);
      float ns = fmaf(sn, cF,  cs * sF);
      cs = nc; sn = ns;
    }
#pragma unroll
    for (int t = 0; t < 4; ++t) {
      cdt[t] = ndt[t]; cx[t] = nx[t]; cbr[t] = nbr[t]; cbi[t] = nbi[t];
      ccr[t] = ncr[t]; cci[t] = nci[t];
    }
  }
  if (c == NCH - 1) {
    fstate[((size_t)b * DI + d) * DS + j]      = sr;
    fstate[((size_t)b * DI + d) * DS + j + 16] = si;
  }
}

// ---------------- gate (y * silu(z)) + LayerNorm, bf16 output ----------------
__global__ __launch_bounds__(256) void gate_ln(const float* __restrict__ y,
                                               const float* __restrict__ zb,
                                               const float* __restrict__ lw,
                                               const float* __restrict__ lb,
                                               unsigned short* __restrict__ o) {
  int tok = blockIdx.x;
  int t = threadIdx.x;
  float g[8];
  float sum = 0.f, sq = 0.f;
#pragma unroll
  for (int i = 0; i < 8; ++i) {
    int dd = t + i * 256;
    float yv = y[(size_t)tok * DI + dd];
    float zv = zb[(size_t)tok * DI + dd];
    float sg = zv / (1.f + __expf(-zv));
    float v = yv * sg;
    g[i] = v; sum += v; sq += v * v;
  }
#pragma unroll
  for (int off = 32; off; off >>= 1) { sum += __shfl_xor(sum, off); sq += __shfl_xor(sq, off); }
  __shared__ float rs[4], rq[4];
  int w = t >> 6;
  if ((t & 63) == 0) { rs[w] = sum; rq[w] = sq; }
  __syncthreads();
  sum = rs[0] + rs[1] + rs[2] + rs[3];
  sq  = rq[0] + rq[1] + rq[2] + rq[3];
  float mu = sum * (1.f / DI);
  float var = sq * (1.f / DI) - mu * mu;
  float rstd = rsqrtf(var + 1e-5f);
#pragma unroll
  for (int i = 0; i < 8; ++i) {
    int dd = t + i * 256;
    o[(size_t)tok * DI + dd] = f2bf((g[i] - mu) * rstd * lw[dd] + lb[dd]);
  }
}

// ---------------- launch ----------------
extern "C" void kernel_launch(void* const* d_in, const int* in_sizes, int n_in,
                              void* d_out, int out_size, void* d_ws, size_t ws_size,
                              hipStream_t stream) {
  const float* x       = (const float*)d_in[0];
  const float* W_in    = (const float*)d_in[1];
  const float* A_log   = (const float*)d_in[2];
  const float* W_B     = (const float*)d_in[3];
  const float* W_C     = (const float*)d_in[4];
  const float* W_dt    = (const float*)d_in[5];
  const float* b_dt    = (const float*)d_in[6];
  const float* dt_bias = (const float*)d_in[7];
  const float* rope    = (const float*)d_in[8];
  const float* ln_w    = (const float*)d_in[9];
  const float* ln_b    = (const float*)d_in[10];
  const float* W_out   = (const float*)d_in[11];
  float* out = (float*)d_out;
  float* ws = (float*)d_ws;

  // workspace layout (float offsets); overlays noted. Max = 12,189,696 f = 48.8 MB (proven R3)
  float* xs   = ws;                                   // [0, 2097152)
  float* zb   = ws + 2097152;                         // [2097152, 4194304)
  float* dts  = ws + 4194304;                         // [4194304, 6291456)
  float* bcb  = ws + 6291456;                         // [6291456, 6356992)
  unsigned short* wob  = (unsigned short*)(ws + 6356992);  // 2M bf16   [.., 7405568)
  unsigned short* xb   = (unsigned short*)(ws + 7405568);  // 1M bf16   [.., 7929856)
  unsigned short* wcat = (unsigned short*)(ws + 7929856);  // 6.42M bf16 [.., 11141120)
  float* Pbuf = ws + 7929856;                         // 3145728 f, alias wcat (dead after GEMM)
  float* Sbuf = ws + 11141120;                        // 1048576 f  [.., 12189696)
  float* yb   = ws + 7929856;                         // 2097152 f, alias Pbuf (dead after p2)
  unsigned short* lnb = (unsigned short*)(ws + 10027008);  // 2M bf16, dead Pbuf tail
  float* fstate = out + (size_t)TOK * DM;

  // 1) fused bf16 casts (x, W_in, W_dt, W_B, W_C, W_out)
  fused_cast<<<4640, 256, 0, stream>>>(x, W_in, W_dt, W_B, W_C, W_out, xb, wcat, wob);
  // 2) fused input GEMM, 64x64 tiles, 1568 blocks, XCD-swizzled (MT = TOK/64 = 16)
  gemm_mfma<64, 64, 16, true><<<(NFUSED / 64) * (TOK / 64), 256, 0, stream>>>(
      xb, wcat, DM, xs, zb, dts, bcb, b_dt, dt_bias, nullptr, 0);
  // 3) chunked scan with 4-step register-group prefetch
  scan_p1<<<NCH * 256, 256, 0, stream>>>(xs, dts, bcb, A_log, rope, Pbuf);
  scan_p2<<<NPAIR / 256, 256, 0, stream>>>(Pbuf, Sbuf);
  scan_p3<<<NCH * 256, 256, 0, stream>>>(xs, dts, bcb, A_log, rope, Sbuf, yb, fstate);
  // 4) gate + LN (bf16 out)
  gate_ln<<<TOK, 256, 0, stream>>>(yb, zb, ln_w, ln_b, lnb);
  // 5) out = ln @ W_out^T, 64x64 tiles, 256 blocks, XCD-swizzled
  gemm_mfma<64, 64, 16, false><<<(DM / 64) * (TOK / 64), 256, 0, stream>>>(
      lnb, wob, DI, nullptr, nullptr, nullptr, nullptr, nullptr, nullptr, out, DM);
}

// Round 7
// 237.502 us; speedup vs baseline: 1.6416x; 1.1545x over previous
//
#include <hip/hip_runtime.h>
#include <math.h>

// Problem constants
#define B_SZ 2
#define SEQ 512
#define DM 1024
#define DI 2048
#define DS 32
#define TOK (B_SZ*SEQ)        // 1024
#define NCH 8                 // scan chunks
#define CLEN (SEQ/NCH)        // 64
#define NG (CLEN/4)           // 16 groups of 4 steps
#define NPAIR (B_SZ*DI*16)    // 65536 (d, rope-pair) chains

// fused weight layout (rows of K=1024, bf16):
//   [0,4096) W_in | [4096,6144) W_dt | [6144,6176) W_B | [6176,6208) W_C | [6208,6272) pad
#define NFUSED 6272

__device__ __forceinline__ unsigned short f2bf(float f) {
  unsigned int u = __builtin_bit_cast(unsigned int, f);
  unsigned int r = u + 0x7fffu + ((u >> 16) & 1u);   // RNE (inputs finite)
  return (unsigned short)(r >> 16);
}

// DPP row-rotate add: sums over the 16-lane row with 4 VALU ops (no LDS pipe).
template<int CTRL>
__device__ __forceinline__ float row_ror_add(float x) {
  int s = __builtin_amdgcn_update_dpp(0, __builtin_bit_cast(int, x), CTRL, 0xf, 0xf, false);
  return x + __builtin_bit_cast(float, s);
}
__device__ __forceinline__ float row16_sum(float v) {
  v = row_ror_add<0x121>(v);   // row_ror:1
  v = row_ror_add<0x122>(v);   // row_ror:2
  v = row_ror_add<0x124>(v);   // row_ror:4
  v = row_ror_add<0x128>(v);   // row_ror:8
  return v;
}

// ---------------- fused fp32 -> bf16 cast of all 6 tensors, 8 elems/thread ----------------
__global__ __launch_bounds__(256) void fused_cast(const float* __restrict__ x,
                                                  const float* __restrict__ W_in,
                                                  const float* __restrict__ W_dt,
                                                  const float* __restrict__ W_B,
                                                  const float* __restrict__ W_C,
                                                  const float* __restrict__ W_out,
                                                  unsigned short* __restrict__ xb,
                                                  unsigned short* __restrict__ wcat,
                                                  unsigned short* __restrict__ wob) {
  int g = blockIdx.x * 256 + threadIdx.x;
  const float* s; unsigned short* dd; int off;
  if      (g <  131072) { s = x;     dd = xb;             off = 0; }
  else if (g <  655360) { s = W_in;  dd = wcat;           off = 131072; }
  else if (g <  917504) { s = W_dt;  dd = wcat + 4194304; off = 655360; }
  else if (g <  921600) { s = W_B;   dd = wcat + 6291456; off = 917504; }
  else if (g <  925696) { s = W_C;   dd = wcat + 6324224; off = 921600; }
  else if (g < 1187840) { s = W_out; dd = wob;            off = 925696; }
  else return;
  int i = g - off;
  float4 a = ((const float4*)s)[i * 2];
  float4 b = ((const float4*)s)[i * 2 + 1];
  union { unsigned short us[8]; uint4 v; } o;
  o.us[0] = f2bf(a.x); o.us[1] = f2bf(a.y); o.us[2] = f2bf(a.z); o.us[3] = f2bf(a.w);
  o.us[4] = f2bf(b.x); o.us[5] = f2bf(b.y); o.us[6] = f2bf(b.z); o.us[7] = f2bf(b.w);
  ((uint4*)dd)[i] = o.v;
}

// ---------------- bf16 MFMA GEMM (C = A * B^T) ----------------
typedef __attribute__((ext_vector_type(8))) short  frag8;
typedef __attribute__((ext_vector_type(4))) float  facc4;

__device__ __forceinline__ void gload_lds16(const unsigned short* g, unsigned short* l) {
  __builtin_amdgcn_global_load_lds((const __attribute__((address_space(1))) unsigned int*)g,
                                   (__attribute__((address_space(3))) unsigned int*)l, 16, 0, 0);
}

__device__ __forceinline__ float softplus_fast(float v) {
  return fmaxf(v, 0.f) + __logf(1.f + __expf(-fabsf(v)));
}

template<int BMt, int BNt, int MT, bool ROUTE>
__global__ __launch_bounds__(256) void gemm_mfma(const unsigned short* __restrict__ A,
                                                 const unsigned short* __restrict__ Bw,
                                                 int K,
                                                 float* __restrict__ o_xs,
                                                 float* __restrict__ o_zb,
                                                 float* __restrict__ o_dts,
                                                 float* __restrict__ o_bcb,
                                                 const float* __restrict__ b_dt,
                                                 const float* __restrict__ dt_bias,
                                                 float* __restrict__ o_c, int ldc) {
  constexpr int FM = BMt / 32, FN = BNt / 32;
  constexpr int IA = BMt / 64, IB = BNt / 64;
  __shared__ __align__(16) unsigned short As[BMt * 32];
  __shared__ __align__(16) unsigned short Bs[BNt * 32];
  const int tid = threadIdx.x;
  const int w = tid >> 6, lane = tid & 63;
  const int wm = w >> 1, wn = w & 1;
  const int bid = blockIdx.x;
  const int Wk = (bid & 7) * ((int)gridDim.x >> 3) + (bid >> 3);
  const int m0 = (Wk % MT) * BMt;
  const int n0 = (Wk / MT) * BNt;
  const int r = lane & 15, q = lane >> 4;
  const int grow = lane >> 2, gk = (lane & 3) * 8;
  facc4 acc[FM][FN] = {};
  const unsigned short* Ag = A + (size_t)m0 * K + gk;
  const unsigned short* Bg = Bw + (size_t)n0 * K + gk;

  for (int k0 = 0; k0 < K; k0 += 32) {
#pragma unroll
    for (int i = 0; i < IA; ++i) {
      int ch = i * 4 + w;
      gload_lds16(Ag + (size_t)(ch * 16 + grow) * K + k0, &As[ch * 512]);
    }
#pragma unroll
    for (int i = 0; i < IB; ++i) {
      int ch = i * 4 + w;
      gload_lds16(Bg + (size_t)(ch * 16 + grow) * K + k0, &Bs[ch * 512]);
    }
    __syncthreads();
    frag8 af[FM], bf[FN];
#pragma unroll
    for (int i = 0; i < FM; ++i)
      af[i] = *(const frag8*)&As[(wm * (BMt / 2) + i * 16 + r) * 32 + q * 8];
#pragma unroll
    for (int jj = 0; jj < FN; ++jj)
      bf[jj] = *(const frag8*)&Bs[(wn * (BNt / 2) + jj * 16 + r) * 32 + q * 8];
#pragma unroll
    for (int i = 0; i < FM; ++i)
#pragma unroll
      for (int jj = 0; jj < FN; ++jj)
        acc[i][jj] = __builtin_amdgcn_mfma_f32_16x16x32_bf16(af[i], bf[jj], acc[i][jj], 0, 0, 0);
    __syncthreads();
  }

#pragma unroll
  for (int i = 0; i < FM; ++i) {
#pragma unroll
    for (int jj = 0; jj < FN; ++jj) {
      int n = n0 + wn * (BNt / 2) + jj * 16 + r;
      int mb = m0 + wm * (BMt / 2) + i * 16 + q * 4;
      if (ROUTE) {
        if (n < 2048) {
#pragma unroll
          for (int rg = 0; rg < 4; ++rg)
            o_xs[(size_t)(mb + rg) * DI + n] = acc[i][jj][rg];
        } else if (n < 4096) {
#pragma unroll
          for (int rg = 0; rg < 4; ++rg)
            o_zb[(size_t)(mb + rg) * DI + (n - 2048)] = acc[i][jj][rg];
        } else if (n < 6144) {
          int d = n - 4096;
          float bias = b_dt[d] + dt_bias[d];
#pragma unroll
          for (int rg = 0; rg < 4; ++rg)
            o_dts[(size_t)(mb + rg) * DI + d] = softplus_fast(acc[i][jj][rg] + bias);
        } else if (n < 6176) {
#pragma unroll
          for (int rg = 0; rg < 4; ++rg)
            o_bcb[(size_t)(mb + rg) * DS + (n - 6144)] = acc[i][jj][rg];
        } else if (n < 6208) {
#pragma unroll
          for (int rg = 0; rg < 4; ++rg)
            o_bcb[(size_t)TOK * DS + (size_t)(mb + rg) * DS + (n - 6176)] = acc[i][jj][rg];
        }
      } else {
#pragma unroll
        for (int rg = 0; rg < 4; ++rg)
          o_c[(size_t)(mb + rg) * ldc + n] = acc[i][jj][rg];
      }
    }
  }
}

// ---------------- chunked scan: 2 chains/lane (channels d, d+16), DPP reduce, rcp ----------------
// Grid: NCH * 128 blocks. Block: 32 channels (dbase..dbase+31), 16 rope-pairs each.
// Lane: j = tid&15 (rope pair, = DPP row position), dl = tid>>4; chains dA=dbase+dl, dB=dA+16.

__global__ __launch_bounds__(256) void scan_p1(const float* __restrict__ xs,
                                               const float* __restrict__ dts,
                                               const float* __restrict__ bcb,
                                               const float* __restrict__ A_log,
                                               const float* __restrict__ rope,
                                               float* __restrict__ Pbuf) {
  const int blk = blockIdx.x;           // 1024
  const int c = blk >> 7;
  const int sub = blk & 127;
  const int b = sub >> 6;
  const int dbase = (sub & 63) << 5;
  const int dl = threadIdx.x >> 4;
  const int j = threadIdx.x & 15;
  const int dA = dbase + dl;
  const int dB = dA + 16;
  const int l0 = c * CLEN;

  const float ArA = -0.5f * expf(A_log[dA * DS + j]);
  const float AiA = -0.5f * expf(A_log[dA * DS + j + 16]);
  const float ArB = -0.5f * expf(A_log[dB * DS + j]);
  const float AiB = -0.5f * expf(A_log[dB * DS + j + 16]);
  const float fr = rope[j];
  float sn, cs, sF, cF;
  sincosf((float)l0 * fr, &sn, &cs);
  sincosf(fr, &sF, &cF);

  const size_t base = (size_t)(b * SEQ + l0);
  const float* dtpA = dts + base * DI + dA;   // chain B at +16
  const float* xpA  = xs  + base * DI + dA;
  const float* Brp  = bcb + base * DS + j;    // shared across chains
  const float* Bip  = Brp + 16;

  float p00A = 1.f, p01A = 0.f, p10A = 0.f, p11A = 1.f, urA = 0.f, uiA = 0.f;
  float p00B = 1.f, p01B = 0.f, p10B = 0.f, p11B = 1.f, urB = 0.f, uiB = 0.f;

  float cdtA[4], cdtB[4], cxA[4], cxB[4], cbr[4], cbi[4];
#pragma unroll
  for (int t = 0; t < 4; ++t) {
    cdtA[t] = dtpA[t * DI]; cdtB[t] = dtpA[t * DI + 16];
    cxA[t]  = xpA[t * DI];  cxB[t]  = xpA[t * DI + 16];
    cbr[t]  = Brp[t * DS];  cbi[t]  = Bip[t * DS];
  }

  for (int g = 0; g < NG; ++g) {
    const int gb = ((g + 1 < NG) ? g + 1 : g) * 4;
    float ndtA[4], ndtB[4], nxA[4], nxB[4], nbr[4], nbi[4];
#pragma unroll
    for (int t = 0; t < 4; ++t) {
      ndtA[t] = dtpA[(gb + t) * DI]; ndtB[t] = dtpA[(gb + t) * DI + 16];
      nxA[t]  = xpA[(gb + t) * DI];  nxB[t]  = xpA[(gb + t) * DI + 16];
      nbr[t]  = Brp[(gb + t) * DS];  nbi[t]  = Bip[(gb + t) * DS];
    }
#pragma unroll
    for (int t = 0; t < 4; ++t) {
      const float Br = cbr[t], Bi = cbi[t];
      // chain A
      {
        float dtd = cdtA[t];
        float hr = dtd * ArA, hi = dtd * AiA;
        float invr = __builtin_amdgcn_rcpf(1.f - hr);
        float invi = __builtin_amdgcn_rcpf(1.f - hi);
        float Abr = (1.f + hr) * invr;
        float Abi = (1.f + hi) * invi;
        float dx = dtd * cxA[t];
        float bxr = dx * invr * Br;
        float bxi = dx * invi * Bi;
        float tr = fmaf(Abr, urA, bxr);
        float ti = fmaf(Abi, uiA, bxi);
        urA = tr * cs - ti * sn;
        uiA = tr * sn + ti * cs;
        float q00 = Abr * p00A, q01 = Abr * p01A;
        float q10 = Abi * p10A, q11 = Abi * p11A;
        p00A = q00 * cs - q10 * sn; p10A = q00 * sn + q10 * cs;
        p01A = q01 * cs - q11 * sn; p11A = q01 * sn + q11 * cs;
      }
      // chain B
      {
        float dtd = cdtB[t];
        float hr = dtd * ArB, hi = dtd * AiB;
        float invr = __builtin_amdgcn_rcpf(1.f - hr);
        float invi = __builtin_amdgcn_rcpf(1.f - hi);
        float Abr = (1.f + hr) * invr;
        float Abi = (1.f + hi) * invi;
        float dx = dtd * cxB[t];
        float bxr = dx * invr * Br;
        float bxi = dx * invi * Bi;
        float tr = fmaf(Abr, urB, bxr);
        float ti = fmaf(Abi, uiB, bxi);
        urB = tr * cs - ti * sn;
        uiB = tr * sn + ti * cs;
        float q00 = Abr * p00B, q01 = Abr * p01B;
        float q10 = Abi * p10B, q11 = Abi * p11B;
        p00B = q00 * cs - q10 * sn; p10B = q00 * sn + q10 * cs;
        p01B = q01 * cs - q11 * sn; p11B = q01 * sn + q11 * cs;
      }
      // shared rotation advance
      float nc = fmaf(cs, cF, -sn * sF);
      float ns = fmaf(sn, cF,  cs * sF);
      cs = nc; sn = ns;
    }
#pragma unroll
    for (int t = 0; t < 4; ++t) {
      cdtA[t] = ndtA[t]; cdtB[t] = ndtB[t]; cxA[t] = nxA[t]; cxB[t] = nxB[t];
      cbr[t] = nbr[t]; cbi[t] = nbi[t];
    }
  }
  const int pairA = (b * DI + dA) * 16 + j;
  const int pairB = (b * DI + dB) * 16 + j;
  Pbuf[(c * 6 + 0) * NPAIR + pairA] = p00A;
  Pbuf[(c * 6 + 1) * NPAIR + pairA] = p01A;
  Pbuf[(c * 6 + 2) * NPAIR + pairA] = p10A;
  Pbuf[(c * 6 + 3) * NPAIR + pairA] = p11A;
  Pbuf[(c * 6 + 4) * NPAIR + pairA] = urA;
  Pbuf[(c * 6 + 5) * NPAIR + pairA] = uiA;
  Pbuf[(c * 6 + 0) * NPAIR + pairB] = p00B;
  Pbuf[(c * 6 + 1) * NPAIR + pairB] = p01B;
  Pbuf[(c * 6 + 2) * NPAIR + pairB] = p10B;
  Pbuf[(c * 6 + 3) * NPAIR + pairB] = p11B;
  Pbuf[(c * 6 + 4) * NPAIR + pairB] = urB;
  Pbuf[(c * 6 + 5) * NPAIR + pairB] = uiB;
}

__global__ __launch_bounds__(256) void scan_p3(const float* __restrict__ xs,
                                               const float* __restrict__ dts,
                                               const float* __restrict__ bcb,
                                               const float* __restrict__ A_log,
                                               const float* __restrict__ rope,
                                               const float* __restrict__ Pbuf,
                                               float* __restrict__ y,
                                               float* __restrict__ fstate) {
  const int blk = blockIdx.x;           // 1024
  const int c = blk >> 7;
  const int sub = blk & 127;
  const int b = sub >> 6;
  const int dbase = (sub & 63) << 5;
  const int dl = threadIdx.x >> 4;
  const int j = threadIdx.x & 15;
  const int dA = dbase + dl;
  const int dB = dA + 16;
  const int l0 = c * CLEN;

  const float ArA = -0.5f * expf(A_log[dA * DS + j]);
  const float AiA = -0.5f * expf(A_log[dA * DS + j + 16]);
  const float ArB = -0.5f * expf(A_log[dB * DS + j]);
  const float AiB = -0.5f * expf(A_log[dB * DS + j + 16]);
  const float fr = rope[j];
  float sn, cs, sF, cF;
  sincosf((float)l0 * fr, &sn, &cs);
  sincosf(fr, &sF, &cF);

  const size_t base = (size_t)(b * SEQ + l0);
  const float* dtpA = dts + base * DI + dA;
  const float* xpA  = xs  + base * DI + dA;
  const float* Brp  = bcb + base * DS + j;
  const float* Bip  = Brp + 16;
  const float* Crp  = bcb + (size_t)TOK * DS + base * DS + j;
  const float* Cip  = Crp + 16;
  float* ypA = y + base * DI + dA;

  // compose entry state from prior chunks (replaces scan_p2)
  const int pairA = (b * DI + dA) * 16 + j;
  const int pairB = (b * DI + dB) * 16 + j;
  float srA = 0.f, siA = 0.f, srB = 0.f, siB = 0.f;
  for (int k = 0; k < c; ++k) {
    float p00 = Pbuf[(k * 6 + 0) * NPAIR + pairA];
    float p01 = Pbuf[(k * 6 + 1) * NPAIR + pairA];
    float p10 = Pbuf[(k * 6 + 2) * NPAIR + pairA];
    float p11 = Pbuf[(k * 6 + 3) * NPAIR + pairA];
    float ur  = Pbuf[(k * 6 + 4) * NPAIR + pairA];
    float ui  = Pbuf[(k * 6 + 5) * NPAIR + pairA];
    float nr = p00 * srA + p01 * siA + ur;
    float ni = p10 * srA + p11 * siA + ui;
    srA = nr; siA = ni;
    p00 = Pbuf[(k * 6 + 0) * NPAIR + pairB];
    p01 = Pbuf[(k * 6 + 1) * NPAIR + pairB];
    p10 = Pbuf[(k * 6 + 2) * NPAIR + pairB];
    p11 = Pbuf[(k * 6 + 3) * NPAIR + pairB];
    ur  = Pbuf[(k * 6 + 4) * NPAIR + pairB];
    ui  = Pbuf[(k * 6 + 5) * NPAIR + pairB];
    nr = p00 * srB + p01 * siB + ur;
    ni = p10 * srB + p11 * siB + ui;
    srB = nr; siB = ni;
  }

  float cdtA[4], cdtB[4], cxA[4], cxB[4], cbr[4], cbi[4], ccr[4], cci[4];
#pragma unroll
  for (int t = 0; t < 4; ++t) {
    cdtA[t] = dtpA[t * DI]; cdtB[t] = dtpA[t * DI + 16];
    cxA[t]  = xpA[t * DI];  cxB[t]  = xpA[t * DI + 16];
    cbr[t]  = Brp[t * DS];  cbi[t]  = Bip[t * DS];
    ccr[t]  = Crp[t * DS];  cci[t]  = Cip[t * DS];
  }

  for (int g = 0; g < NG; ++g) {
    const int gb = ((g + 1 < NG) ? g + 1 : g) * 4;
    float ndtA[4], ndtB[4], nxA[4], nxB[4], nbr[4], nbi[4], ncr[4], nci[4];
#pragma unroll
    for (int t = 0; t < 4; ++t) {
      ndtA[t] = dtpA[(gb + t) * DI]; ndtB[t] = dtpA[(gb + t) * DI + 16];
      nxA[t]  = xpA[(gb + t) * DI];  nxB[t]  = xpA[(gb + t) * DI + 16];
      nbr[t]  = Brp[(gb + t) * DS];  nbi[t]  = Bip[(gb + t) * DS];
      ncr[t]  = Crp[(gb + t) * DS];  nci[t]  = Cip[(gb + t) * DS];
    }
#pragma unroll
    for (int t = 0; t < 4; ++t) {
      const float Br = cbr[t], Bi = cbi[t], Cr = ccr[t], Ci = cci[t];
      float pA, pB;
      // chain A
      {
        float dtd = cdtA[t];
        float hr = dtd * ArA, hi = dtd * AiA;
        float invr = __builtin_amdgcn_rcpf(1.f - hr);
        float invi = __builtin_amdgcn_rcpf(1.f - hi);
        float Abr = (1.f + hr) * invr;
        float Abi = (1.f + hi) * invi;
        float dx = dtd * cxA[t];
        float bxr = dx * invr * Br;
        float bxi = dx * invi * Bi;
        float tr = fmaf(Abr, srA, bxr);
        float ti = fmaf(Abi, siA, bxi);
        srA = tr * cs - ti * sn;
        siA = tr * sn + ti * cs;
        pA = srA * Cr + siA * Ci;
      }
      // chain B
      {
        float dtd = cdtB[t];
        float hr = dtd * ArB, hi = dtd * AiB;
        float invr = __builtin_amdgcn_rcpf(1.f - hr);
        float invi = __builtin_amdgcn_rcpf(1.f - hi);
        float Abr = (1.f + hr) * invr;
        float Abi = (1.f + hi) * invi;
        float dx = dtd * cxB[t];
        float bxr = dx * invr * Br;
        float bxi = dx * invi * Bi;
        float tr = fmaf(Abr, srB, bxr);
        float ti = fmaf(Abi, siB, bxi);
        srB = tr * cs - ti * sn;
        siB = tr * sn + ti * cs;
        pB = srB * Cr + siB * Ci;
      }
      pA = row16_sum(pA);
      pB = row16_sum(pB);
      if (j == 0) {
        ypA[(g * 4 + t) * DI]      = pA;
        ypA[(g * 4 + t) * DI + 16] = pB;
      }
      float nc = fmaf(cs, cF, -sn * sF);
      float ns = fmaf(sn, cF,  cs * sF);
      cs = nc; sn = ns;
    }
#pragma unroll
    for (int t = 0; t < 4; ++t) {
      cdtA[t] = ndtA[t]; cdtB[t] = ndtB[t]; cxA[t] = nxA[t]; cxB[t] = nxB[t];
      cbr[t] = nbr[t]; cbi[t] = nbi[t]; ccr[t] = ncr[t]; cci[t] = nci[t];
    }
  }
  if (c == NCH - 1) {
    fstate[((size_t)b * DI + dA) * DS + j]      = srA;
    fstate[((size_t)b * DI + dA) * DS + j + 16] = siA;
    fstate[((size_t)b * DI + dB) * DS + j]      = srB;
    fstate[((size_t)b * DI + dB) * DS + j + 16] = siB;
  }
}

// ---------------- gate (y * silu(z)) + LayerNorm, bf16 output ----------------
__global__ __launch_bounds__(256) void gate_ln(const float* __restrict__ y,
                                               const float* __restrict__ zb,
                                               const float* __restrict__ lw,
                                               const float* __restrict__ lb,
                                               unsigned short* __restrict__ o) {
  int tok = blockIdx.x;
  int t = threadIdx.x;
  float g[8];
  float sum = 0.f, sq = 0.f;
#pragma unroll
  for (int i = 0; i < 8; ++i) {
    int dd = t + i * 256;
    float yv = y[(size_t)tok * DI + dd];
    float zv = zb[(size_t)tok * DI + dd];
    float sg = zv / (1.f + __expf(-zv));
    float v = yv * sg;
    g[i] = v; sum += v; sq += v * v;
  }
#pragma unroll
  for (int off = 32; off; off >>= 1) { sum += __shfl_xor(sum, off); sq += __shfl_xor(sq, off); }
  __shared__ float rs[4], rq[4];
  int w = t >> 6;
  if ((t & 63) == 0) { rs[w] = sum; rq[w] = sq; }
  __syncthreads();
  sum = rs[0] + rs[1] + rs[2] + rs[3];
  sq  = rq[0] + rq[1] + rq[2] + rq[3];
  float mu = sum * (1.f / DI);
  float var = sq * (1.f / DI) - mu * mu;
  float rstd = rsqrtf(var + 1e-5f);
#pragma unroll
  for (int i = 0; i < 8; ++i) {
    int dd = t + i * 256;
    o[(size_t)tok * DI + dd] = f2bf((g[i] - mu) * rstd * lw[dd] + lb[dd]);
  }
}

// ---------------- launch ----------------
extern "C" void kernel_launch(void* const* d_in, const int* in_sizes, int n_in,
                              void* d_out, int out_size, void* d_ws, size_t ws_size,
                              hipStream_t stream) {
  const float* x       = (const float*)d_in[0];
  const float* W_in    = (const float*)d_in[1];
  const float* A_log   = (const float*)d_in[2];
  const float* W_B     = (const float*)d_in[3];
  const float* W_C     = (const float*)d_in[4];
  const float* W_dt    = (const float*)d_in[5];
  const float* b_dt    = (const float*)d_in[6];
  const float* dt_bias = (const float*)d_in[7];
  const float* rope    = (const float*)d_in[8];
  const float* ln_w    = (const float*)d_in[9];
  const float* ln_b    = (const float*)d_in[10];
  const float* W_out   = (const float*)d_in[11];
  float* out = (float*)d_out;
  float* ws = (float*)d_ws;

  // workspace layout (float offsets); overlays noted. Max = 12,189,696 f = 48.8 MB (proven R3)
  float* xs   = ws;                                   // [0, 2097152)
  float* zb   = ws + 2097152;                         // [2097152, 4194304)
  float* dts  = ws + 4194304;                         // [4194304, 6291456)
  float* bcb  = ws + 6291456;                         // [6291456, 6356992)
  unsigned short* wob  = (unsigned short*)(ws + 6356992);  // 2M bf16   [.., 7405568)
  unsigned short* xb   = (unsigned short*)(ws + 7405568);  // 1M bf16   [.., 7929856)
  unsigned short* wcat = (unsigned short*)(ws + 7929856);  // 6.42M bf16 [.., 11141120)
  float* Pbuf = ws + 7929856;                         // 3145728 f, alias wcat (dead after GEMM)
  float* yb   = ws + 11141120;                        // 2097152 f  [.., 13238272) — live with Pbuf
  unsigned short* lnb = (unsigned short*)(ws + 13238272);  // 2M bf16 [.., 14286848)
  float* fstate = out + (size_t)TOK * DM;

  // 1) fused bf16 casts (x, W_in, W_dt, W_B, W_C, W_out)
  fused_cast<<<4640, 256, 0, stream>>>(x, W_in, W_dt, W_B, W_C, W_out, xb, wcat, wob);
  // 2) fused input GEMM, 64x64 tiles, 1568 blocks, XCD-swizzled (MT = TOK/64 = 16)
  gemm_mfma<64, 64, 16, true><<<(NFUSED / 64) * (TOK / 64), 256, 0, stream>>>(
      xb, wcat, DM, xs, zb, dts, bcb, b_dt, dt_bias, nullptr, 0);
  // 3) chunked scan: p1 (local P,u) then p3 (compose entry inline + re-scan)
  scan_p1<<<NCH * 128, 256, 0, stream>>>(xs, dts, bcb, A_log, rope, Pbuf);
  scan_p3<<<NCH * 128, 256, 0, stream>>>(xs, dts, bcb, A_log, rope, Pbuf, yb, fstate);
  // 4) gate + LN (bf16 out)
  gate_ln<<<TOK, 256, 0, stream>>>(yb, zb, ln_w, ln_b, lnb);
  // 5) out = ln @ W_out^T, 64x64 tiles, 256 blocks, XCD-swizzled
  gemm_mfma<64, 64, 16, false><<<(DM / 64) * (TOK / 64), 256, 0, stream>>>(
      lnb, wob, DI, nullptr, nullptr, nullptr, nullptr, nullptr, nullptr, out, DM);
}

// Round 8
// 230.583 us; speedup vs baseline: 1.6908x; 1.0300x over previous
//
#include <hip/hip_runtime.h>
#include <math.h>

// Problem constants
#define B_SZ 2
#define SEQ 512
#define DM 1024
#define DI 2048
#define DS 32
#define TOK (B_SZ*SEQ)        // 1024
#define NCH 8                 // scan chunks
#define CLEN (SEQ/NCH)        // 64
#define NPAIR (B_SZ*DI*16)    // 65536 (d, rope-pair) chains

// fused weight layout (rows of K=1024, bf16):
//   [0,4096) W_in | [4096,6144) W_dt | [6144,6176) W_B | [6176,6208) W_C | [6208,6272) pad
#define NFUSED 6272

__device__ __forceinline__ unsigned short f2bf(float f) {
  unsigned int u = __builtin_bit_cast(unsigned int, f);
  unsigned int r = u + 0x7fffu + ((u >> 16) & 1u);   // RNE (inputs finite)
  return (unsigned short)(r >> 16);
}

// DPP row-rotate add: sums over the 16-lane row with 4 VALU ops (no LDS pipe).
template<int CTRL>
__device__ __forceinline__ float row_ror_add(float x) {
  int s = __builtin_amdgcn_update_dpp(0, __builtin_bit_cast(int, x), CTRL, 0xf, 0xf, false);
  return x + __builtin_bit_cast(float, s);
}
__device__ __forceinline__ float row16_sum(float v) {
  v = row_ror_add<0x121>(v);   // row_ror:1
  v = row_ror_add<0x122>(v);   // row_ror:2
  v = row_ror_add<0x124>(v);   // row_ror:4
  v = row_ror_add<0x128>(v);   // row_ror:8
  return v;
}

// ---------------- fused fp32 -> bf16 cast of all 6 tensors, 8 elems/thread ----------------
__global__ __launch_bounds__(256) void fused_cast(const float* __restrict__ x,
                                                  const float* __restrict__ W_in,
                                                  const float* __restrict__ W_dt,
                                                  const float* __restrict__ W_B,
                                                  const float* __restrict__ W_C,
                                                  const float* __restrict__ W_out,
                                                  unsigned short* __restrict__ xb,
                                                  unsigned short* __restrict__ wcat,
                                                  unsigned short* __restrict__ wob) {
  int g = blockIdx.x * 256 + threadIdx.x;
  const float* s; unsigned short* dd; int off;
  if      (g <  131072) { s = x;     dd = xb;             off = 0; }
  else if (g <  655360) { s = W_in;  dd = wcat;           off = 131072; }
  else if (g <  917504) { s = W_dt;  dd = wcat + 4194304; off = 655360; }
  else if (g <  921600) { s = W_B;   dd = wcat + 6291456; off = 917504; }
  else if (g <  925696) { s = W_C;   dd = wcat + 6324224; off = 921600; }
  else if (g < 1187840) { s = W_out; dd = wob;            off = 925696; }
  else return;
  int i = g - off;
  float4 a = ((const float4*)s)[i * 2];
  float4 b = ((const float4*)s)[i * 2 + 1];
  union { unsigned short us[8]; uint4 v; } o;
  o.us[0] = f2bf(a.x); o.us[1] = f2bf(a.y); o.us[2] = f2bf(a.z); o.us[3] = f2bf(a.w);
  o.us[4] = f2bf(b.x); o.us[5] = f2bf(b.y); o.us[6] = f2bf(b.z); o.us[7] = f2bf(b.w);
  ((uint4*)dd)[i] = o.v;
}

// ---------------- bf16 MFMA GEMM (C = A * B^T) ----------------
typedef __attribute__((ext_vector_type(8))) short  frag8;
typedef __attribute__((ext_vector_type(4))) float  facc4;

__device__ __forceinline__ void gload_lds16(const unsigned short* g, unsigned short* l) {
  __builtin_amdgcn_global_load_lds((const __attribute__((address_space(1))) unsigned int*)g,
                                   (__attribute__((address_space(3))) unsigned int*)l, 16, 0, 0);
}
__device__ __forceinline__ void gload_lds16f(const float* g, float* l) {
  __builtin_amdgcn_global_load_lds((const __attribute__((address_space(1))) unsigned int*)g,
                                   (__attribute__((address_space(3))) unsigned int*)l, 16, 0, 0);
}

__device__ __forceinline__ float softplus_fast(float v) {
  return fmaxf(v, 0.f) + __logf(1.f + __expf(-fabsf(v)));
}

template<int BMt, int BNt, int MT, bool ROUTE>
__global__ __launch_bounds__(256) void gemm_mfma(const unsigned short* __restrict__ A,
                                                 const unsigned short* __restrict__ Bw,
                                                 int K,
                                                 float* __restrict__ o_xs,
                                                 float* __restrict__ o_zb,
                                                 float* __restrict__ o_dts,
                                                 float* __restrict__ o_bcb,
                                                 const float* __restrict__ b_dt,
                                                 const float* __restrict__ dt_bias,
                                                 float* __restrict__ o_c, int ldc) {
  constexpr int FM = BMt / 32, FN = BNt / 32;
  constexpr int IA = BMt / 64, IB = BNt / 64;
  __shared__ __align__(16) unsigned short As[BMt * 32];
  __shared__ __align__(16) unsigned short Bs[BNt * 32];
  const int tid = threadIdx.x;
  const int w = tid >> 6, lane = tid & 63;
  const int wm = w >> 1, wn = w & 1;
  const int bid = blockIdx.x;
  const int Wk = (bid & 7) * ((int)gridDim.x >> 3) + (bid >> 3);
  const int m0 = (Wk % MT) * BMt;
  const int n0 = (Wk / MT) * BNt;
  const int r = lane & 15, q = lane >> 4;
  const int grow = lane >> 2, gk = (lane & 3) * 8;
  facc4 acc[FM][FN] = {};
  const unsigned short* Ag = A + (size_t)m0 * K + gk;
  const unsigned short* Bg = Bw + (size_t)n0 * K + gk;

  for (int k0 = 0; k0 < K; k0 += 32) {
#pragma unroll
    for (int i = 0; i < IA; ++i) {
      int ch = i * 4 + w;
      gload_lds16(Ag + (size_t)(ch * 16 + grow) * K + k0, &As[ch * 512]);
    }
#pragma unroll
    for (int i = 0; i < IB; ++i) {
      int ch = i * 4 + w;
      gload_lds16(Bg + (size_t)(ch * 16 + grow) * K + k0, &Bs[ch * 512]);
    }
    __syncthreads();
    frag8 af[FM], bf[FN];
#pragma unroll
    for (int i = 0; i < FM; ++i)
      af[i] = *(const frag8*)&As[(wm * (BMt / 2) + i * 16 + r) * 32 + q * 8];
#pragma unroll
    for (int jj = 0; jj < FN; ++jj)
      bf[jj] = *(const frag8*)&Bs[(wn * (BNt / 2) + jj * 16 + r) * 32 + q * 8];
#pragma unroll
    for (int i = 0; i < FM; ++i)
#pragma unroll
      for (int jj = 0; jj < FN; ++jj)
        acc[i][jj] = __builtin_amdgcn_mfma_f32_16x16x32_bf16(af[i], bf[jj], acc[i][jj], 0, 0, 0);
    __syncthreads();
  }

#pragma unroll
  for (int i = 0; i < FM; ++i) {
#pragma unroll
    for (int jj = 0; jj < FN; ++jj) {
      int n = n0 + wn * (BNt / 2) + jj * 16 + r;
      int mb = m0 + wm * (BMt / 2) + i * 16 + q * 4;
      if (ROUTE) {
        if (n < 2048) {
#pragma unroll
          for (int rg = 0; rg < 4; ++rg)
            o_xs[(size_t)(mb + rg) * DI + n] = acc[i][jj][rg];
        } else if (n < 4096) {
#pragma unroll
          for (int rg = 0; rg < 4; ++rg)
            o_zb[(size_t)(mb + rg) * DI + (n - 2048)] = acc[i][jj][rg];
        } else if (n < 6144) {
          int d = n - 4096;
          float bias = b_dt[d] + dt_bias[d];
#pragma unroll
          for (int rg = 0; rg < 4; ++rg)
            o_dts[(size_t)(mb + rg) * DI + d] = softplus_fast(acc[i][jj][rg] + bias);
        } else if (n < 6176) {
#pragma unroll
          for (int rg = 0; rg < 4; ++rg)
            o_bcb[(size_t)(mb + rg) * DS + (n - 6144)] = acc[i][jj][rg];
        } else if (n < 6208) {
#pragma unroll
          for (int rg = 0; rg < 4; ++rg)
            o_bcb[(size_t)TOK * DS + (size_t)(mb + rg) * DS + (n - 6176)] = acc[i][jj][rg];
        }
      } else {
#pragma unroll
        for (int rg = 0; rg < 4; ++rg)
          o_c[(size_t)(mb + rg) * ldc + n] = acc[i][jj][rg];
      }
    }
  }
}

// ---------------- chunked scan: LDS-staged chunk, load-free hot loop ----------------
// Block: 32 channels (dbase..dbase+31) x 16 rope-pairs, one (b, chunk).
// LDS layout (floats): x[64][32] @0 | dt[64][32] @2048 | B[64][32] @4096 | (p3) C[64][32] @6144
// Lane: j = tid&15 (DPP row pos), dl = tid>>4 (0..15); chains dA=dbase+dl, dB=dA+16.

__global__ __launch_bounds__(256) void scan_p1(const float* __restrict__ xs,
                                               const float* __restrict__ dts,
                                               const float* __restrict__ bcb,
                                               const float* __restrict__ A_log,
                                               const float* __restrict__ rope,
                                               float* __restrict__ Pbuf) {
  __shared__ __align__(16) float lds[6144];
  const int blk = blockIdx.x;           // 896 = 7 chunks x 128
  const int c = blk >> 7;               // 0..6 (chunk 7's P,u never consumed)
  const int sub = blk & 127;
  const int b = sub >> 6;
  const int dbase = (sub & 63) << 5;
  const int tid = threadIdx.x;
  const int wv = tid >> 6, lane = tid & 63;
  const int dl = tid >> 4;              // hmm — see note below (recomputed after staging)
  const int j = tid & 15;
  const int l0 = c * CLEN;
  const size_t base = (size_t)(b * SEQ + l0);

  // --- stage x, dt, B (24 KB) ---
  {
    int row = wv * 16 + (lane >> 3);
    int col = (lane & 7) << 2;
#pragma unroll
    for (int k = 0; k < 2; ++k) {
      gload_lds16f(xs  + (base + row + k * 8) * DI + dbase + col, &lds[(wv * 16 + k * 8) * 32]);
      gload_lds16f(dts + (base + row + k * 8) * DI + dbase + col, &lds[2048 + (wv * 16 + k * 8) * 32]);
    }
#pragma unroll
    for (int k = 0; k < 2; ++k) {
      int seg = wv * 2 + k;             // bc chunk is contiguous 8 KB
      gload_lds16f(bcb + base * DS + seg * 256 + lane * 4, &lds[4096 + seg * 256]);
    }
  }

  const int dA = dbase + (dl & 15);
  const int dB = dA + 16;
  const float ArA = -0.5f * expf(A_log[dA * DS + j]);
  const float AiA = -0.5f * expf(A_log[dA * DS + j + 16]);
  const float ArB = -0.5f * expf(A_log[dB * DS + j]);
  const float AiB = -0.5f * expf(A_log[dB * DS + j + 16]);
  const float fr = rope[j];
  float sn, cs, sF, cF;
  sincosf((float)l0 * fr, &sn, &cs);
  sincosf(fr, &sF, &cF);
  __syncthreads();                      // drains global_load_lds (vmcnt)

  float p00A = 1.f, p01A = 0.f, p10A = 0.f, p11A = 1.f, urA = 0.f, uiA = 0.f;
  float p00B = 1.f, p01B = 0.f, p10B = 0.f, p11B = 1.f, urB = 0.f, uiB = 0.f;
  const int ca = dl & 15;

#pragma unroll 4
  for (int tt = 0; tt < CLEN; ++tt) {
    const int ro = tt * 32;
    float dtdA = lds[2048 + ro + ca];
    float dtdB = lds[2048 + ro + ca + 16];
    float xinA = lds[ro + ca];
    float xinB = lds[ro + ca + 16];
    float Br   = lds[4096 + ro + j];
    float Bi   = lds[4096 + ro + j + 16];
    // chain A
    {
      float hr = dtdA * ArA, hi = dtdA * AiA;
      float invr = __builtin_amdgcn_rcpf(1.f - hr);
      float invi = __builtin_amdgcn_rcpf(1.f - hi);
      float Abr = (1.f + hr) * invr;
      float Abi = (1.f + hi) * invi;
      float dx = dtdA * xinA;
      float bxr = dx * invr * Br;
      float bxi = dx * invi * Bi;
      float tr = fmaf(Abr, urA, bxr);
      float ti = fmaf(Abi, uiA, bxi);
      urA = tr * cs - ti * sn;
      uiA = tr * sn + ti * cs;
      float q00 = Abr * p00A, q01 = Abr * p01A;
      float q10 = Abi * p10A, q11 = Abi * p11A;
      p00A = q00 * cs - q10 * sn; p10A = q00 * sn + q10 * cs;
      p01A = q01 * cs - q11 * sn; p11A = q01 * sn + q11 * cs;
    }
    // chain B
    {
      float hr = dtdB * ArB, hi = dtdB * AiB;
      float invr = __builtin_amdgcn_rcpf(1.f - hr);
      float invi = __builtin_amdgcn_rcpf(1.f - hi);
      float Abr = (1.f + hr) * invr;
      float Abi = (1.f + hi) * invi;
      float dx = dtdB * xinB;
      float bxr = dx * invr * Br;
      float bxi = dx * invi * Bi;
      float tr = fmaf(Abr, urB, bxr);
      float ti = fmaf(Abi, uiB, bxi);
      urB = tr * cs - ti * sn;
      uiB = tr * sn + ti * cs;
      float q00 = Abr * p00B, q01 = Abr * p01B;
      float q10 = Abi * p10B, q11 = Abi * p11B;
      p00B = q00 * cs - q10 * sn; p10B = q00 * sn + q10 * cs;
      p01B = q01 * cs - q11 * sn; p11B = q01 * sn + q11 * cs;
    }
    float nc = fmaf(cs, cF, -sn * sF);
    float ns = fmaf(sn, cF,  cs * sF);
    cs = nc; sn = ns;
  }
  const int pairA = (b * DI + dA) * 16 + j;
  const int pairB = (b * DI + dB) * 16 + j;
  Pbuf[(c * 6 + 0) * NPAIR + pairA] = p00A;
  Pbuf[(c * 6 + 1) * NPAIR + pairA] = p01A;
  Pbuf[(c * 6 + 2) * NPAIR + pairA] = p10A;
  Pbuf[(c * 6 + 3) * NPAIR + pairA] = p11A;
  Pbuf[(c * 6 + 4) * NPAIR + pairA] = urA;
  Pbuf[(c * 6 + 5) * NPAIR + pairA] = uiA;
  Pbuf[(c * 6 + 0) * NPAIR + pairB] = p00B;
  Pbuf[(c * 6 + 1) * NPAIR + pairB] = p01B;
  Pbuf[(c * 6 + 2) * NPAIR + pairB] = p10B;
  Pbuf[(c * 6 + 3) * NPAIR + pairB] = p11B;
  Pbuf[(c * 6 + 4) * NPAIR + pairB] = urB;
  Pbuf[(c * 6 + 5) * NPAIR + pairB] = uiB;
}

__global__ __launch_bounds__(256) void scan_p3(const float* __restrict__ xs,
                                               const float* __restrict__ dts,
                                               const float* __restrict__ bcb,
                                               const float* __restrict__ A_log,
                                               const float* __restrict__ rope,
                                               const float* __restrict__ Pbuf,
                                               float* __restrict__ y,
                                               float* __restrict__ fstate) {
  __shared__ __align__(16) float lds[8192];
  const int blk = blockIdx.x;           // 1024
  const int c = blk >> 7;
  const int sub = blk & 127;
  const int b = sub >> 6;
  const int dbase = (sub & 63) << 5;
  const int tid = threadIdx.x;
  const int wv = tid >> 6, lane = tid & 63;
  const int j = tid & 15;
  const int l0 = c * CLEN;
  const size_t base = (size_t)(b * SEQ + l0);

  // --- stage x, dt, B, C (32 KB) ---
  {
    int row = wv * 16 + (lane >> 3);
    int col = (lane & 7) << 2;
#pragma unroll
    for (int k = 0; k < 2; ++k) {
      gload_lds16f(xs  + (base + row + k * 8) * DI + dbase + col, &lds[(wv * 16 + k * 8) * 32]);
      gload_lds16f(dts + (base + row + k * 8) * DI + dbase + col, &lds[2048 + (wv * 16 + k * 8) * 32]);
    }
#pragma unroll
    for (int k = 0; k < 2; ++k) {
      int seg = wv * 2 + k;
      gload_lds16f(bcb + base * DS + seg * 256 + lane * 4, &lds[4096 + seg * 256]);
      gload_lds16f(bcb + (size_t)TOK * DS + base * DS + seg * 256 + lane * 4, &lds[6144 + seg * 256]);
    }
  }

  const int ca = (tid >> 4) & 15;
  const int dA = dbase + ca;
  const int dB = dA + 16;
  const float ArA = -0.5f * expf(A_log[dA * DS + j]);
  const float AiA = -0.5f * expf(A_log[dA * DS + j + 16]);
  const float ArB = -0.5f * expf(A_log[dB * DS + j]);
  const float AiB = -0.5f * expf(A_log[dB * DS + j + 16]);
  const float fr = rope[j];
  float sn, cs, sF, cF;
  sincosf((float)l0 * fr, &sn, &cs);
  sincosf(fr, &sF, &cF);

  // compose entry state from prior chunks (merged scan_p2)
  const int pairA = (b * DI + dA) * 16 + j;
  const int pairB = (b * DI + dB) * 16 + j;
  float srA = 0.f, siA = 0.f, srB = 0.f, siB = 0.f;
  for (int k = 0; k < c; ++k) {
    float p00 = Pbuf[(k * 6 + 0) * NPAIR + pairA];
    float p01 = Pbuf[(k * 6 + 1) * NPAIR + pairA];
    float p10 = Pbuf[(k * 6 + 2) * NPAIR + pairA];
    float p11 = Pbuf[(k * 6 + 3) * NPAIR + pairA];
    float ur  = Pbuf[(k * 6 + 4) * NPAIR + pairA];
    float ui  = Pbuf[(k * 6 + 5) * NPAIR + pairA];
    float nr = p00 * srA + p01 * siA + ur;
    float ni = p10 * srA + p11 * siA + ui;
    srA = nr; siA = ni;
    p00 = Pbuf[(k * 6 + 0) * NPAIR + pairB];
    p01 = Pbuf[(k * 6 + 1) * NPAIR + pairB];
    p10 = Pbuf[(k * 6 + 2) * NPAIR + pairB];
    p11 = Pbuf[(k * 6 + 3) * NPAIR + pairB];
    ur  = Pbuf[(k * 6 + 4) * NPAIR + pairB];
    ui  = Pbuf[(k * 6 + 5) * NPAIR + pairB];
    nr = p00 * srB + p01 * siB + ur;
    ni = p10 * srB + p11 * siB + ui;
    srB = nr; siB = ni;
  }
  __syncthreads();                      // drains global_load_lds

  float* ypA = y + base * DI + dA;

#pragma unroll 4
  for (int tt = 0; tt < CLEN; ++tt) {
    const int ro = tt * 32;
    float dtdA = lds[2048 + ro + ca];
    float dtdB = lds[2048 + ro + ca + 16];
    float xinA = lds[ro + ca];
    float xinB = lds[ro + ca + 16];
    float Br   = lds[4096 + ro + j];
    float Bi   = lds[4096 + ro + j + 16];
    float Cr   = lds[6144 + ro + j];
    float Ci   = lds[6144 + ro + j + 16];
    float pA, pB;
    // chain A
    {
      float hr = dtdA * ArA, hi = dtdA * AiA;
      float invr = __builtin_amdgcn_rcpf(1.f - hr);
      float invi = __builtin_amdgcn_rcpf(1.f - hi);
      float Abr = (1.f + hr) * invr;
      float Abi = (1.f + hi) * invi;
      float dx = dtdA * xinA;
      float bxr = dx * invr * Br;
      float bxi = dx * invi * Bi;
      float tr = fmaf(Abr, srA, bxr);
      float ti = fmaf(Abi, siA, bxi);
      srA = tr * cs - ti * sn;
      siA = tr * sn + ti * cs;
      pA = srA * Cr + siA * Ci;
    }
    // chain B
    {
      float hr = dtdB * ArB, hi = dtdB * AiB;
      float invr = __builtin_amdgcn_rcpf(1.f - hr);
      float invi = __builtin_amdgcn_rcpf(1.f - hi);
      float Abr = (1.f + hr) * invr;
      float Abi = (1.f + hi) * invi;
      float dx = dtdB * xinB;
      float bxr = dx * invr * Br;
      float bxi = dx * invi * Bi;
      float tr = fmaf(Abr, srB, bxr);
      float ti = fmaf(Abi, siB, bxi);
      srB = tr * cs - ti * sn;
      siB = tr * sn + ti * cs;
      pB = srB * Cr + siB * Ci;
    }
    pA = row16_sum(pA);
    pB = row16_sum(pB);
    if (j == 0) {
      ypA[tt * DI]      = pA;
      ypA[tt * DI + 16] = pB;
    }
    float nc = fmaf(cs, cF, -sn * sF);
    float ns = fmaf(sn, cF,  cs * sF);
    cs = nc; sn = ns;
  }
  if (c == NCH - 1) {
    fstate[((size_t)b * DI + dA) * DS + j]      = srA;
    fstate[((size_t)b * DI + dA) * DS + j + 16] = siA;
    fstate[((size_t)b * DI + dB) * DS + j]      = srB;
    fstate[((size_t)b * DI + dB) * DS + j + 16] = siB;
  }
}

// ---------------- gate (y * silu(z)) + LayerNorm, bf16 output ----------------
__global__ __launch_bounds__(256) void gate_ln(const float* __restrict__ y,
                                               const float* __restrict__ zb,
                                               const float* __restrict__ lw,
                                               const float* __restrict__ lb,
                                               unsigned short* __restrict__ o) {
  int tok = blockIdx.x;
  int t = threadIdx.x;
  float g[8];
  float sum = 0.f, sq = 0.f;
#pragma unroll
  for (int i = 0; i < 8; ++i) {
    int dd = t + i * 256;
    float yv = y[(size_t)tok * DI + dd];
    float zv = zb[(size_t)tok * DI + dd];
    float sg = zv / (1.f + __expf(-zv));
    float v = yv * sg;
    g[i] = v; sum += v; sq += v * v;
  }
#pragma unroll
  for (int off = 32; off; off >>= 1) { sum += __shfl_xor(sum, off); sq += __shfl_xor(sq, off); }
  __shared__ float rs[4], rq[4];
  int w = t >> 6;
  if ((t & 63) == 0) { rs[w] = sum; rq[w] = sq; }
  __syncthreads();
  sum = rs[0] + rs[1] + rs[2] + rs[3];
  sq  = rq[0] + rq[1] + rq[2] + rq[3];
  float mu = sum * (1.f / DI);
  float var = sq * (1.f / DI) - mu * mu;
  float rstd = rsqrtf(var + 1e-5f);
#pragma unroll
  for (int i = 0; i < 8; ++i) {
    int dd = t + i * 256;
    o[(size_t)tok * DI + dd] = f2bf((g[i] - mu) * rstd * lw[dd] + lb[dd]);
  }
}

// ---------------- launch ----------------
extern "C" void kernel_launch(void* const* d_in, const int* in_sizes, int n_in,
                              void* d_out, int out_size, void* d_ws, size_t ws_size,
                              hipStream_t stream) {
  const float* x       = (const float*)d_in[0];
  const float* W_in    = (const float*)d_in[1];
  const float* A_log   = (const float*)d_in[2];
  const float* W_B     = (const float*)d_in[3];
  const float* W_C     = (const float*)d_in[4];
  const float* W_dt    = (const float*)d_in[5];
  const float* b_dt    = (const float*)d_in[6];
  const float* dt_bias = (const float*)d_in[7];
  const float* rope    = (const float*)d_in[8];
  const float* ln_w    = (const float*)d_in[9];
  const float* ln_b    = (const float*)d_in[10];
  const float* W_out   = (const float*)d_in[11];
  float* out = (float*)d_out;
  float* ws = (float*)d_ws;

  // workspace layout (float offsets); overlays noted
  float* xs   = ws;                                   // [0, 2097152)
  float* zb   = ws + 2097152;                         // [2097152, 4194304)
  float* dts  = ws + 4194304;                         // [4194304, 6291456)
  float* bcb  = ws + 6291456;                         // [6291456, 6356992)
  unsigned short* wob  = (unsigned short*)(ws + 6356992);  // 2M bf16   [.., 7405568)
  unsigned short* xb   = (unsigned short*)(ws + 7405568);  // 1M bf16   [.., 7929856)
  unsigned short* wcat = (unsigned short*)(ws + 7929856);  // 6.42M bf16 [.., 11141120)
  float* Pbuf = ws + 7929856;                         // 3145728 f, alias wcat (dead after GEMM)
  float* yb   = ws + 11141120;                        // 2097152 f  [.., 13238272)
  unsigned short* lnb = (unsigned short*)(ws + 13238272);  // 2M bf16 [.., 14286848)
  float* fstate = out + (size_t)TOK * DM;

  // 1) fused bf16 casts (x, W_in, W_dt, W_B, W_C, W_out)
  fused_cast<<<4640, 256, 0, stream>>>(x, W_in, W_dt, W_B, W_C, W_out, xb, wcat, wob);
  // 2) fused input GEMM, 64x64 tiles, 1568 blocks, XCD-swizzled (MT = TOK/64 = 16)
  gemm_mfma<64, 64, 16, true><<<(NFUSED / 64) * (TOK / 64), 256, 0, stream>>>(
      xb, wcat, DM, xs, zb, dts, bcb, b_dt, dt_bias, nullptr, 0);
  // 3) chunked scan: p1 (local P,u; chunk 7 skipped) then p3 (compose entry inline + re-scan)
  scan_p1<<<(NCH - 1) * 128, 256, 0, stream>>>(xs, dts, bcb, A_log, rope, Pbuf);
  scan_p3<<<NCH * 128, 256, 0, stream>>>(xs, dts, bcb, A_log, rope, Pbuf, yb, fstate);
  // 4) gate + LN (bf16 out)
  gate_ln<<<TOK, 256, 0, stream>>>(yb, zb, ln_w, ln_b, lnb);
  // 5) out = ln @ W_out^T, 64x64 tiles, 256 blocks, XCD-swizzled
  gemm_mfma<64, 64, 16, false><<<(DM / 64) * (TOK / 64), 256, 0, stream>>>(
      lnb, wob, DI, nullptr, nullptr, nullptr, nullptr, nullptr, nullptr, out, DM);
}

// Round 10
// 218.911 us; speedup vs baseline: 1.7810x; 1.0533x over previous
//
#include <hip/hip_runtime.h>
#include <math.h>

// Problem constants
#define B_SZ 2
#define SEQ 512
#define DM 1024
#define DI 2048
#define DS 32
#define TOK (B_SZ*SEQ)        // 1024
#define NCH 8                 // scan chunks
#define CLEN (SEQ/NCH)        // 64
#define NPAIRH 32768          // (b, d-pair, j) chain-pair ids

// fused weight layout (rows of K=1024, bf16):
//   [0,4096) W_in | [4096,6144) W_dt | [6144,6176) W_B | [6176,6208) W_C | [6208,6272) pad
#define NFUSED 6272

typedef float v2f __attribute__((ext_vector_type(2)));

__device__ __forceinline__ unsigned short f2bf(float f) {
  unsigned int u = __builtin_bit_cast(unsigned int, f);
  unsigned int r = u + 0x7fffu + ((u >> 16) & 1u);   // RNE (inputs finite)
  return (unsigned short)(r >> 16);
}

// DPP row-rotate add: sums over the 16-lane row with 4 VALU ops (no LDS pipe).
template<int CTRL>
__device__ __forceinline__ float row_ror_add(float x) {
  int s = __builtin_amdgcn_update_dpp(0, __builtin_bit_cast(int, x), CTRL, 0xf, 0xf, false);
  return x + __builtin_bit_cast(float, s);
}
__device__ __forceinline__ float row16_sum(float v) {
  v = row_ror_add<0x121>(v);
  v = row_ror_add<0x122>(v);
  v = row_ror_add<0x124>(v);
  v = row_ror_add<0x128>(v);
  return v;
}

// ---------------- fused fp32 -> bf16 cast of all 6 tensors, 8 elems/thread ----------------
__global__ __launch_bounds__(256) void fused_cast(const float* __restrict__ x,
                                                  const float* __restrict__ W_in,
                                                  const float* __restrict__ W_dt,
                                                  const float* __restrict__ W_B,
                                                  const float* __restrict__ W_C,
                                                  const float* __restrict__ W_out,
                                                  unsigned short* __restrict__ xb,
                                                  unsigned short* __restrict__ wcat,
                                                  unsigned short* __restrict__ wob) {
  int g = blockIdx.x * 256 + threadIdx.x;
  const float* s; unsigned short* dd; int off;
  if      (g <  131072) { s = x;     dd = xb;             off = 0; }
  else if (g <  655360) { s = W_in;  dd = wcat;           off = 131072; }
  else if (g <  917504) { s = W_dt;  dd = wcat + 4194304; off = 655360; }
  else if (g <  921600) { s = W_B;   dd = wcat + 6291456; off = 917504; }
  else if (g <  925696) { s = W_C;   dd = wcat + 6324224; off = 921600; }
  else if (g < 1187840) { s = W_out; dd = wob;            off = 925696; }
  else return;
  int i = g - off;
  float4 a = ((const float4*)s)[i * 2];
  float4 b = ((const float4*)s)[i * 2 + 1];
  union { unsigned short us[8]; uint4 v; } o;
  o.us[0] = f2bf(a.x); o.us[1] = f2bf(a.y); o.us[2] = f2bf(a.z); o.us[3] = f2bf(a.w);
  o.us[4] = f2bf(b.x); o.us[5] = f2bf(b.y); o.us[6] = f2bf(b.z); o.us[7] = f2bf(b.w);
  ((uint4*)dd)[i] = o.v;
}

// ---------------- bf16 MFMA GEMM (C = A * B^T) ----------------
typedef __attribute__((ext_vector_type(8))) short  frag8;
typedef __attribute__((ext_vector_type(4))) float  facc4;

__device__ __forceinline__ void gload_lds16(const unsigned short* g, unsigned short* l) {
  __builtin_amdgcn_global_load_lds((const __attribute__((address_space(1))) unsigned int*)g,
                                   (__attribute__((address_space(3))) unsigned int*)l, 16, 0, 0);
}
__device__ __forceinline__ void gload_lds16f(const float* g, float* l) {
  __builtin_amdgcn_global_load_lds((const __attribute__((address_space(1))) unsigned int*)g,
                                   (__attribute__((address_space(3))) unsigned int*)l, 16, 0, 0);
}

__device__ __forceinline__ float softplus_fast(float v) {
  return fmaxf(v, 0.f) + __logf(1.f + __expf(-fabsf(v)));
}

template<int BMt, int BNt, int MT, bool ROUTE>
__global__ __launch_bounds__(256) void gemm_mfma(const unsigned short* __restrict__ A,
                                                 const unsigned short* __restrict__ Bw,
                                                 int K,
                                                 float* __restrict__ o_xs,
                                                 float* __restrict__ o_zb,
                                                 float* __restrict__ o_dts,
                                                 float* __restrict__ o_bcb,
                                                 const float* __restrict__ b_dt,
                                                 const float* __restrict__ dt_bias,
                                                 float* __restrict__ o_c, int ldc) {
  constexpr int FM = BMt / 32, FN = BNt / 32;
  constexpr int IA = BMt / 64, IB = BNt / 64;
  __shared__ __align__(16) unsigned short As[BMt * 32];
  __shared__ __align__(16) unsigned short Bs[BNt * 32];
  const int tid = threadIdx.x;
  const int w = tid >> 6, lane = tid & 63;
  const int wm = w >> 1, wn = w & 1;
  const int bid = blockIdx.x;
  const int Wk = (bid & 7) * ((int)gridDim.x >> 3) + (bid >> 3);
  const int m0 = (Wk % MT) * BMt;
  const int n0 = (Wk / MT) * BNt;
  const int r = lane & 15, q = lane >> 4;
  const int grow = lane >> 2, gk = (lane & 3) * 8;
  facc4 acc[FM][FN] = {};
  const unsigned short* Ag = A + (size_t)m0 * K + gk;
  const unsigned short* Bg = Bw + (size_t)n0 * K + gk;

  for (int k0 = 0; k0 < K; k0 += 32) {
#pragma unroll
    for (int i = 0; i < IA; ++i) {
      int ch = i * 4 + w;
      gload_lds16(Ag + (size_t)(ch * 16 + grow) * K + k0, &As[ch * 512]);
    }
#pragma unroll
    for (int i = 0; i < IB; ++i) {
      int ch = i * 4 + w;
      gload_lds16(Bg + (size_t)(ch * 16 + grow) * K + k0, &Bs[ch * 512]);
    }
    __syncthreads();
    frag8 af[FM], bf[FN];
#pragma unroll
    for (int i = 0; i < FM; ++i)
      af[i] = *(const frag8*)&As[(wm * (BMt / 2) + i * 16 + r) * 32 + q * 8];
#pragma unroll
    for (int jj = 0; jj < FN; ++jj)
      bf[jj] = *(const frag8*)&Bs[(wn * (BNt / 2) + jj * 16 + r) * 32 + q * 8];
#pragma unroll
    for (int i = 0; i < FM; ++i)
#pragma unroll
      for (int jj = 0; jj < FN; ++jj)
        acc[i][jj] = __builtin_amdgcn_mfma_f32_16x16x32_bf16(af[i], bf[jj], acc[i][jj], 0, 0, 0);
    __syncthreads();
  }

#pragma unroll
  for (int i = 0; i < FM; ++i) {
#pragma unroll
    for (int jj = 0; jj < FN; ++jj) {
      int n = n0 + wn * (BNt / 2) + jj * 16 + r;
      int mb = m0 + wm * (BMt / 2) + i * 16 + q * 4;
      if (ROUTE) {
        if (n < 2048) {
#pragma unroll
          for (int rg = 0; rg < 4; ++rg)
            o_xs[(size_t)(mb + rg) * DI + n] = acc[i][jj][rg];
        } else if (n < 4096) {
#pragma unroll
          for (int rg = 0; rg < 4; ++rg)
            o_zb[(size_t)(mb + rg) * DI + (n - 2048)] = acc[i][jj][rg];
        } else if (n < 6144) {
          int d = n - 4096;
          float bias = b_dt[d] + dt_bias[d];
#pragma unroll
          for (int rg = 0; rg < 4; ++rg)
            o_dts[(size_t)(mb + rg) * DI + d] = softplus_fast(acc[i][jj][rg] + bias);
        } else if (n < 6176) {
#pragma unroll
          for (int rg = 0; rg < 4; ++rg)
            o_bcb[(size_t)(mb + rg) * DS + (n - 6144)] = acc[i][jj][rg];
        } else if (n < 6208) {
#pragma unroll
          for (int rg = 0; rg < 4; ++rg)
            o_bcb[(size_t)TOK * DS + (size_t)(mb + rg) * DS + (n - 6176)] = acc[i][jj][rg];
        }
      } else {
#pragma unroll
        for (int rg = 0; rg < 4; ++rg)
          o_c[(size_t)(mb + rg) * ldc + n] = acc[i][jj][rg];
      }
    }
  }
}

// ---------------- chunked scan: LDS-staged chunk, v2f packed chains (d, d+1) ----------------
// Block: 32 channels (dbase..dbase+31) x 16 rope-pairs, one (b, chunk).
// LDS (floats): x[64][32] @0 | dt @2048 | B @4096 | (p3) C @6144.
// Lane: j = tid&15 (DPP row pos), ca = (tid>>4)&15; chains dA = dbase+2*ca, dA+1.

__global__ __launch_bounds__(256) void scan_p1(const float* __restrict__ xs,
                                               const float* __restrict__ dts,
                                               const float* __restrict__ bcb,
                                               const float* __restrict__ A_log,
                                               const float* __restrict__ rope,
                                               float* __restrict__ Pbuf) {
  __shared__ __align__(16) float lds[6144];
  const int blk = blockIdx.x;           // 896 = 7 chunks x 128 (chunk 7's P,u never consumed)
  const int c = blk >> 7;
  const int sub = blk & 127;
  const int b = sub >> 6;
  const int dbase = (sub & 63) << 5;
  const int tid = threadIdx.x;
  const int wv = tid >> 6, lane = tid & 63;
  const int j = tid & 15;
  const int ca = (tid >> 4) & 15;
  const int l0 = c * CLEN;
  const size_t base = (size_t)(b * SEQ + l0);

  // --- stage x, dt, B (24 KB) ---
  {
    int row = wv * 16 + (lane >> 3);
    int col = (lane & 7) << 2;
#pragma unroll
    for (int k = 0; k < 2; ++k) {
      gload_lds16f(xs  + (base + row + k * 8) * DI + dbase + col, &lds[(wv * 16 + k * 8) * 32]);
      gload_lds16f(dts + (base + row + k * 8) * DI + dbase + col, &lds[2048 + (wv * 16 + k * 8) * 32]);
    }
#pragma unroll
    for (int k = 0; k < 2; ++k) {
      int seg = wv * 2 + k;             // bc chunk is contiguous 8 KB
      gload_lds16f(bcb + base * DS + seg * 256 + lane * 4, &lds[4096 + seg * 256]);
    }
  }

  const int dA = dbase + 2 * ca;        // chains dA, dA+1
  v2f Ar, Ai;
  Ar.x = -0.5f * expf(A_log[dA * DS + j]);
  Ar.y = -0.5f * expf(A_log[(dA + 1) * DS + j]);
  Ai.x = -0.5f * expf(A_log[dA * DS + j + 16]);
  Ai.y = -0.5f * expf(A_log[(dA + 1) * DS + j + 16]);
  const float fr = rope[j];
  float sn, cs, sF, cF;
  sincosf((float)l0 * fr, &sn, &cs);
  sincosf(fr, &sF, &cF);
  __syncthreads();                      // drains global_load_lds (vmcnt)

  v2f p00 = {1.f, 1.f}, p01 = {0.f, 0.f}, p10 = {0.f, 0.f}, p11 = {1.f, 1.f};
  v2f ur = {0.f, 0.f}, ui = {0.f, 0.f};

#pragma unroll 4
  for (int tt = 0; tt < CLEN; ++tt) {
    const int ro = tt * 32;
    v2f xin = *(const v2f*)&lds[ro + 2 * ca];
    v2f dtd = *(const v2f*)&lds[2048 + ro + 2 * ca];
    float Br = lds[4096 + ro + j];
    float Bi = lds[4096 + ro + j + 16];
    v2f hr = dtd * Ar, hi = dtd * Ai;
    v2f invr, invi;
    invr.x = __builtin_amdgcn_rcpf(1.f - hr.x);
    invr.y = __builtin_amdgcn_rcpf(1.f - hr.y);
    invi.x = __builtin_amdgcn_rcpf(1.f - hi.x);
    invi.y = __builtin_amdgcn_rcpf(1.f - hi.y);
    v2f Abr = 2.f * invr - 1.f;         // (1+h)/(1-h)
    v2f Abi = 2.f * invi - 1.f;
    v2f dx = dtd * xin;
    v2f bxr = dx * invr * Br;
    v2f bxi = dx * invi * Bi;
    v2f tr = Abr * ur + bxr;
    v2f ti = Abi * ui + bxi;
    ur = tr * cs - ti * sn;
    ui = tr * sn + ti * cs;
    v2f q00 = Abr * p00, q01 = Abr * p01;
    v2f q10 = Abi * p10, q11 = Abi * p11;
    p00 = q00 * cs - q10 * sn; p10 = q00 * sn + q10 * cs;
    p01 = q01 * cs - q11 * sn; p11 = q01 * sn + q11 * cs;
    float nc = fmaf(cs, cF, -sn * sF);
    float ns = fmaf(sn, cF,  cs * sF);
    cs = nc; sn = ns;
  }
  const int pc = (b * 1024 + (dbase >> 1) + ca) * 16 + j;   // chain-pair id
  float2* Pb2 = (float2*)Pbuf;
  Pb2[(c * 6 + 0) * NPAIRH + pc] = make_float2(p00.x, p00.y);
  Pb2[(c * 6 + 1) * NPAIRH + pc] = make_float2(p01.x, p01.y);
  Pb2[(c * 6 + 2) * NPAIRH + pc] = make_float2(p10.x, p10.y);
  Pb2[(c * 6 + 3) * NPAIRH + pc] = make_float2(p11.x, p11.y);
  Pb2[(c * 6 + 4) * NPAIRH + pc] = make_float2(ur.x, ur.y);
  Pb2[(c * 6 + 5) * NPAIRH + pc] = make_float2(ui.x, ui.y);
}

__global__ __launch_bounds__(256) void scan_p3(const float* __restrict__ xs,
                                               const float* __restrict__ dts,
                                               const float* __restrict__ bcb,
                                               const float* __restrict__ A_log,
                                               const float* __restrict__ rope,
                                               const float* __restrict__ Pbuf,
                                               float* __restrict__ y,
                                               float* __restrict__ fstate) {
  __shared__ __align__(16) float lds[8192];
  const int blk = blockIdx.x;           // 1024
  const int c = blk >> 7;
  const int sub = blk & 127;
  const int b = sub >> 6;
  const int dbase = (sub & 63) << 5;
  const int tid = threadIdx.x;
  const int wv = tid >> 6, lane = tid & 63;
  const int j = tid & 15;
  const int ca = (tid >> 4) & 15;
  const int l0 = c * CLEN;
  const size_t base = (size_t)(b * SEQ + l0);

  // --- stage x, dt, B, C (32 KB) ---
  {
    int row = wv * 16 + (lane >> 3);
    int col = (lane & 7) << 2;
#pragma unroll
    for (int k = 0; k < 2; ++k) {
      gload_lds16f(xs  + (base + row + k * 8) * DI + dbase + col, &lds[(wv * 16 + k * 8) * 32]);
      gload_lds16f(dts + (base + row + k * 8) * DI + dbase + col, &lds[2048 + (wv * 16 + k * 8) * 32]);
    }
#pragma unroll
    for (int k = 0; k < 2; ++k) {
      int seg = wv * 2 + k;
      gload_lds16f(bcb + base * DS + seg * 256 + lane * 4, &lds[4096 + seg * 256]);
      gload_lds16f(bcb + (size_t)TOK * DS + base * DS + seg * 256 + lane * 4, &lds[6144 + seg * 256]);
    }
  }

  const int dA = dbase + 2 * ca;
  v2f Ar, Ai;
  Ar.x = -0.5f * expf(A_log[dA * DS + j]);
  Ar.y = -0.5f * expf(A_log[(dA + 1) * DS + j]);
  Ai.x = -0.5f * expf(A_log[dA * DS + j + 16]);
  Ai.y = -0.5f * expf(A_log[(dA + 1) * DS + j + 16]);
  const float fr = rope[j];
  float sn, cs, sF, cF;
  sincosf((float)l0 * fr, &sn, &cs);
  sincosf(fr, &sF, &cF);

  // compose entry state from prior chunks (global float2 loads overlap the staging drain)
  const int pc = (b * 1024 + (dbase >> 1) + ca) * 16 + j;
  const float2* Pb2 = (const float2*)Pbuf;
  v2f sr = {0.f, 0.f}, si = {0.f, 0.f};
  for (int k = 0; k < c; ++k) {
    float2 f;
    f = Pb2[(k * 6 + 0) * NPAIRH + pc]; v2f p00 = {f.x, f.y};
    f = Pb2[(k * 6 + 1) * NPAIRH + pc]; v2f p01 = {f.x, f.y};
    f = Pb2[(k * 6 + 2) * NPAIRH + pc]; v2f p10 = {f.x, f.y};
    f = Pb2[(k * 6 + 3) * NPAIRH + pc]; v2f p11 = {f.x, f.y};
    f = Pb2[(k * 6 + 4) * NPAIRH + pc]; v2f ur  = {f.x, f.y};
    f = Pb2[(k * 6 + 5) * NPAIRH + pc]; v2f ui  = {f.x, f.y};
    v2f nr = p00 * sr + p01 * si + ur;
    v2f ni = p10 * sr + p11 * si + ui;
    sr = nr; si = ni;
  }
  __syncthreads();                      // drains global_load_lds

  float* yp = y + base * DI + dA;

#pragma unroll 4
  for (int tt = 0; tt < CLEN; ++tt) {
    const int ro = tt * 32;
    v2f xin = *(const v2f*)&lds[ro + 2 * ca];
    v2f dtd = *(const v2f*)&lds[2048 + ro + 2 * ca];
    float Br = lds[4096 + ro + j];
    float Bi = lds[4096 + ro + j + 16];
    float Cr = lds[6144 + ro + j];
    float Ci = lds[6144 + ro + j + 16];
    v2f hr = dtd * Ar, hi = dtd * Ai;
    v2f invr, invi;
    invr.x = __builtin_amdgcn_rcpf(1.f - hr.x);
    invr.y = __builtin_amdgcn_rcpf(1.f - hr.y);
    invi.x = __builtin_amdgcn_rcpf(1.f - hi.x);
    invi.y = __builtin_amdgcn_rcpf(1.f - hi.y);
    v2f Abr = 2.f * invr - 1.f;
    v2f Abi = 2.f * invi - 1.f;
    v2f dx = dtd * xin;
    v2f bxr = dx * invr * Br;
    v2f bxi = dx * invi * Bi;
    v2f tr = Abr * sr + bxr;
    v2f ti = Abi * si + bxi;
    sr = tr * cs - ti * sn;
    si = tr * sn + ti * cs;
    v2f p = sr * Cr + si * Ci;
    float pA = row16_sum(p.x);
    float pB = row16_sum(p.y);
    if (j == 0) *(float2*)&yp[tt * DI] = make_float2(pA, pB);
    float nc = fmaf(cs, cF, -sn * sF);
    float ns = fmaf(sn, cF,  cs * sF);
    cs = nc; sn = ns;
  }
  if (c == NCH - 1) {
    fstate[((size_t)b * DI + dA) * DS + j]          = sr.x;
    fstate[((size_t)b * DI + dA) * DS + j + 16]     = si.x;
    fstate[((size_t)b * DI + dA + 1) * DS + j]      = sr.y;
    fstate[((size_t)b * DI + dA + 1) * DS + j + 16] = si.y;
  }
}

// ---------------- gate (y * silu(z)) + LayerNorm, bf16 output ----------------
__global__ __launch_bounds__(256) void gate_ln(const float* __restrict__ y,
                                               const float* __restrict__ zb,
                                               const float* __restrict__ lw,
                                               const float* __restrict__ lb,
                                               unsigned short* __restrict__ o) {
  int tok = blockIdx.x;
  int t = threadIdx.x;
  float g[8];
  float sum = 0.f, sq = 0.f;
#pragma unroll
  for (int i = 0; i < 8; ++i) {
    int dd = t + i * 256;
    float yv = y[(size_t)tok * DI + dd];
    float zv = zb[(size_t)tok * DI + dd];
    float sg = zv / (1.f + __expf(-zv));
    float v = yv * sg;
    g[i] = v; sum += v; sq += v * v;
  }
#pragma unroll
  for (int off = 32; off; off >>= 1) { sum += __shfl_xor(sum, off); sq += __shfl_xor(sq, off); }
  __shared__ float rs[4], rq[4];
  int w = t >> 6;
  if ((t & 63) == 0) { rs[w] = sum; rq[w] = sq; }
  __syncthreads();
  sum = rs[0] + rs[1] + rs[2] + rs[3];
  sq  = rq[0] + rq[1] + rq[2] + rq[3];
  float mu = sum * (1.f / DI);
  float var = sq * (1.f / DI) - mu * mu;
  float rstd = rsqrtf(var + 1e-5f);
#pragma unroll
  for (int i = 0; i < 8; ++i) {
    int dd = t + i * 256;
    o[(size_t)tok * DI + dd] = f2bf((g[i] - mu) * rstd * lw[dd] + lb[dd]);
  }
}

// ---------------- launch ----------------
extern "C" void kernel_launch(void* const* d_in, const int* in_sizes, int n_in,
                              void* d_out, int out_size, void* d_ws, size_t ws_size,
                              hipStream_t stream) {
  const float* x       = (const float*)d_in[0];
  const float* W_in    = (const float*)d_in[1];
  const float* A_log   = (const float*)d_in[2];
  const float* W_B     = (const float*)d_in[3];
  const float* W_C     = (const float*)d_in[4];
  const float* W_dt    = (const float*)d_in[5];
  const float* b_dt    = (const float*)d_in[6];
  const float* dt_bias = (const float*)d_in[7];
  const float* rope    = (const float*)d_in[8];
  const float* ln_w    = (const float*)d_in[9];
  const float* ln_b    = (const float*)d_in[10];
  const float* W_out   = (const float*)d_in[11];
  float* out = (float*)d_out;
  float* ws = (float*)d_ws;

  // workspace layout (float offsets); overlays noted
  float* xs   = ws;                                   // [0, 2097152)
  float* zb   = ws + 2097152;                         // [2097152, 4194304)
  float* dts  = ws + 4194304;                         // [4194304, 6291456)
  float* bcb  = ws + 6291456;                         // [6291456, 6356992)
  unsigned short* wob  = (unsigned short*)(ws + 6356992);  // 2M bf16   [.., 7405568)
  unsigned short* xb   = (unsigned short*)(ws + 7405568);  // 1M bf16   [.., 7929856)
  unsigned short* wcat = (unsigned short*)(ws + 7929856);  // 6.42M bf16 [.., 11141120)
  float* Pbuf = ws + 7929856;                         // 2752512 f used, alias wcat (dead after GEMM)
  float* yb   = ws + 11141120;                        // 2097152 f  [.., 13238272)
  unsigned short* lnb = (unsigned short*)(ws + 13238272);  // 2M bf16 [.., 14286848)
  float* fstate = out + (size_t)TOK * DM;

  // 1) fused bf16 casts (x, W_in, W_dt, W_B, W_C, W_out)
  fused_cast<<<4640, 256, 0, stream>>>(x, W_in, W_dt, W_B, W_C, W_out, xb, wcat, wob);
  // 2) fused input GEMM, 64x64 tiles, 1568 blocks, XCD-swizzled (MT = TOK/64 = 16)
  gemm_mfma<64, 64, 16, true><<<(NFUSED / 64) * (TOK / 64), 256, 0, stream>>>(
      xb, wcat, DM, xs, zb, dts, bcb, b_dt, dt_bias, nullptr, 0);
  // 3) chunked scan: p1 (local P,u; chunk 7 skipped) then p3 (compose entry inline + re-scan)
  scan_p1<<<(NCH - 1) * 128, 256, 0, stream>>>(xs, dts, bcb, A_log, rope, Pbuf);
  scan_p3<<<NCH * 128, 256, 0, stream>>>(xs, dts, bcb, A_log, rope, Pbuf, yb, fstate);
  // 4) gate + LN (bf16 out)
  gate_ln<<<TOK, 256, 0, stream>>>(yb, zb, ln_w, ln_b, lnb);
  // 5) out = ln @ W_out^T, 64x64 tiles, 256 blocks, XCD-swizzled
  gemm_mfma<64, 64, 16, false><<<(DM / 64) * (TOK / 64), 256, 0, stream>>>(
      lnb, wob, DI, nullptr, nullptr, nullptr, nullptr, nullptr, nullptr, out, DM);
}

// Round 11
// 215.897 us; speedup vs baseline: 1.8058x; 1.0140x over previous
//
#include <hip/hip_runtime.h>
#include <math.h>

// Problem constants
#define B_SZ 2
#define SEQ 512
#define DM 1024
#define DI 2048
#define DS 32
#define TOK (B_SZ*SEQ)        // 1024
#define NCH 8                 // scan chunks
#define CLEN (SEQ/NCH)        // 64
#define NPAIRH 32768          // (b, d-pair, j) chain-pair ids

// fused weight layout (rows of K=1024, bf16):
//   [0,4096) W_in | [4096,6144) W_dt | [6144,6176) W_B | [6176,6208) W_C | [6208,6272) pad
#define NFUSED 6272

typedef float v2f __attribute__((ext_vector_type(2)));

__device__ __forceinline__ unsigned short f2bf(float f) {
  unsigned int u = __builtin_bit_cast(unsigned int, f);
  unsigned int r = u + 0x7fffu + ((u >> 16) & 1u);   // RNE (inputs finite)
  return (unsigned short)(r >> 16);
}

// DPP row-rotate add: sums over the 16-lane row with 4 VALU ops (no LDS pipe).
template<int CTRL>
__device__ __forceinline__ float row_ror_add(float x) {
  int s = __builtin_amdgcn_update_dpp(0, __builtin_bit_cast(int, x), CTRL, 0xf, 0xf, false);
  return x + __builtin_bit_cast(float, s);
}
__device__ __forceinline__ float row16_sum(float v) {
  v = row_ror_add<0x121>(v);
  v = row_ror_add<0x122>(v);
  v = row_ror_add<0x124>(v);
  v = row_ror_add<0x128>(v);
  return v;
}

// ---------------- fused fp32 -> bf16 cast of all 6 tensors, 8 elems/thread ----------------
__global__ __launch_bounds__(256) void fused_cast(const float* __restrict__ x,
                                                  const float* __restrict__ W_in,
                                                  const float* __restrict__ W_dt,
                                                  const float* __restrict__ W_B,
                                                  const float* __restrict__ W_C,
                                                  const float* __restrict__ W_out,
                                                  unsigned short* __restrict__ xb,
                                                  unsigned short* __restrict__ wcat,
                                                  unsigned short* __restrict__ wob) {
  int g = blockIdx.x * 256 + threadIdx.x;
  const float* s; unsigned short* dd; int off;
  if      (g <  131072) { s = x;     dd = xb;             off = 0; }
  else if (g <  655360) { s = W_in;  dd = wcat;           off = 131072; }
  else if (g <  917504) { s = W_dt;  dd = wcat + 4194304; off = 655360; }
  else if (g <  921600) { s = W_B;   dd = wcat + 6291456; off = 917504; }
  else if (g <  925696) { s = W_C;   dd = wcat + 6324224; off = 921600; }
  else if (g < 1187840) { s = W_out; dd = wob;            off = 925696; }
  else return;
  int i = g - off;
  float4 a = ((const float4*)s)[i * 2];
  float4 b = ((const float4*)s)[i * 2 + 1];
  union { unsigned short us[8]; uint4 v; } o;
  o.us[0] = f2bf(a.x); o.us[1] = f2bf(a.y); o.us[2] = f2bf(a.z); o.us[3] = f2bf(a.w);
  o.us[4] = f2bf(b.x); o.us[5] = f2bf(b.y); o.us[6] = f2bf(b.z); o.us[7] = f2bf(b.w);
  ((uint4*)dd)[i] = o.v;
}

// ---------------- bf16 MFMA GEMM (C = A * B^T), 64x64 tile, BK=64 ----------------
typedef __attribute__((ext_vector_type(8))) short  frag8;
typedef __attribute__((ext_vector_type(4))) float  facc4;

__device__ __forceinline__ void gload_lds16(const unsigned short* g, unsigned short* l) {
  __builtin_amdgcn_global_load_lds((const __attribute__((address_space(1))) unsigned int*)g,
                                   (__attribute__((address_space(3))) unsigned int*)l, 16, 0, 0);
}
__device__ __forceinline__ void gload_lds16f(const float* g, float* l) {
  __builtin_amdgcn_global_load_lds((const __attribute__((address_space(1))) unsigned int*)g,
                                   (__attribute__((address_space(3))) unsigned int*)l, 16, 0, 0);
}

__device__ __forceinline__ float softplus_fast(float v) {
  return fmaxf(v, 0.f) + __logf(1.f + __expf(-fabsf(v)));
}

// MT m-tiles, NT n-tiles, KSP-way split-K (partials at o_c + ks*MT*64*ldc).
// XCD swizzle: bid&7 -> contiguous work slice per XCD.
template<int MT, int NT, int KSP, bool ROUTE>
__global__ __launch_bounds__(256) void gemm_mfma(const unsigned short* __restrict__ A,
                                                 const unsigned short* __restrict__ Bw,
                                                 int K,
                                                 float* __restrict__ o_xs,
                                                 float* __restrict__ o_zb,
                                                 float* __restrict__ o_dts,
                                                 float* __restrict__ o_bcb,
                                                 const float* __restrict__ b_dt,
                                                 const float* __restrict__ dt_bias,
                                                 float* __restrict__ o_c, int ldc) {
  __shared__ __align__(16) unsigned short As[64 * 64];   // 8 KB
  __shared__ __align__(16) unsigned short Bs[64 * 64];   // 8 KB
  const int tid = threadIdx.x;
  const int w = tid >> 6, lane = tid & 63;
  const int wm = w >> 1, wn = w & 1;
  const int bid = blockIdx.x;
  const int Wk = (bid & 7) * ((int)gridDim.x >> 3) + (bid >> 3);
  const int ks = Wk / (MT * NT);
  const int rem = Wk % (MT * NT);
  const int m0 = (rem % MT) * 64;
  const int n0 = (rem / MT) * 64;
  const int kLen = K / KSP, kBeg = ks * kLen;
  const int r = lane & 15, q = lane >> 4;
  const int srow = lane >> 3;            // staging row-in-chunk (0..7)
  const int scol = (lane & 7) * 8;       // staging k-col (elements)
  facc4 acc[2][2] = {};
  const unsigned short* Ag = A + (size_t)m0 * K + kBeg;
  const unsigned short* Bg = Bw + (size_t)n0 * K + kBeg;

  for (int k0 = 0; k0 < kLen; k0 += 64) {
#pragma unroll
    for (int k = 0; k < 2; ++k) {
      int ch = w * 2 + k;                // 8 chunks of 8 rows x 64 k (1 KB)
      gload_lds16(Ag + (size_t)(ch * 8 + srow) * K + k0 + scol, &As[ch * 512]);
      gload_lds16(Bg + (size_t)(ch * 8 + srow) * K + k0 + scol, &Bs[ch * 512]);
    }
    __syncthreads();                     // drains global_load_lds
#pragma unroll
    for (int kk = 0; kk < 2; ++kk) {
      frag8 af[2], bf[2];
#pragma unroll
      for (int i = 0; i < 2; ++i)
        af[i] = *(const frag8*)&As[(wm * 32 + i * 16 + r) * 64 + kk * 32 + q * 8];
#pragma unroll
      for (int jj = 0; jj < 2; ++jj)
        bf[jj] = *(const frag8*)&Bs[(wn * 32 + jj * 16 + r) * 64 + kk * 32 + q * 8];
#pragma unroll
      for (int i = 0; i < 2; ++i)
#pragma unroll
        for (int jj = 0; jj < 2; ++jj)
          acc[i][jj] = __builtin_amdgcn_mfma_f32_16x16x32_bf16(af[i], bf[jj], acc[i][jj], 0, 0, 0);
    }
    __syncthreads();
  }

#pragma unroll
  for (int i = 0; i < 2; ++i) {
#pragma unroll
    for (int jj = 0; jj < 2; ++jj) {
      int n = n0 + wn * 32 + jj * 16 + r;
      int mb = m0 + wm * 32 + i * 16 + q * 4;
      if (ROUTE) {
        if (n < 2048) {
#pragma unroll
          for (int rg = 0; rg < 4; ++rg)
            o_xs[(size_t)(mb + rg) * DI + n] = acc[i][jj][rg];
        } else if (n < 4096) {
#pragma unroll
          for (int rg = 0; rg < 4; ++rg)
            o_zb[(size_t)(mb + rg) * DI + (n - 2048)] = acc[i][jj][rg];
        } else if (n < 6144) {
          int d = n - 4096;
          float bias = b_dt[d] + dt_bias[d];
#pragma unroll
          for (int rg = 0; rg < 4; ++rg)
            o_dts[(size_t)(mb + rg) * DI + d] = softplus_fast(acc[i][jj][rg] + bias);
        } else if (n < 6176) {
#pragma unroll
          for (int rg = 0; rg < 4; ++rg)
            o_bcb[(size_t)(mb + rg) * DS + (n - 6144)] = acc[i][jj][rg];
        } else if (n < 6208) {
#pragma unroll
          for (int rg = 0; rg < 4; ++rg)
            o_bcb[(size_t)TOK * DS + (size_t)(mb + rg) * DS + (n - 6176)] = acc[i][jj][rg];
        }
      } else {
        float* oc = o_c + (size_t)ks * (MT * 64) * ldc;
#pragma unroll
        for (int rg = 0; rg < 4; ++rg)
          oc[(size_t)(mb + rg) * ldc + n] = acc[i][jj][rg];
      }
    }
  }
}

// ---------------- split-K reduction: out = P0 + P1 (float4) ----------------
__global__ __launch_bounds__(256) void addk(const float* __restrict__ p0,
                                            const float* __restrict__ p1,
                                            float* __restrict__ o) {
  int i = blockIdx.x * 256 + threadIdx.x;
  float4 a = ((const float4*)p0)[i];
  float4 b = ((const float4*)p1)[i];
  ((float4*)o)[i] = make_float4(a.x + b.x, a.y + b.y, a.z + b.z, a.w + b.w);
}

// ---------------- chunked scan: LDS-staged chunk, v2f packed chains (d, d+1) ----------------
__global__ __launch_bounds__(256) void scan_p1(const float* __restrict__ xs,
                                               const float* __restrict__ dts,
                                               const float* __restrict__ bcb,
                                               const float* __restrict__ A_log,
                                               const float* __restrict__ rope,
                                               float* __restrict__ Pbuf) {
  __shared__ __align__(16) float lds[6144];
  const int blk = blockIdx.x;           // 896 = 7 chunks x 128 (chunk 7's P,u never consumed)
  const int c = blk >> 7;
  const int sub = blk & 127;
  const int b = sub >> 6;
  const int dbase = (sub & 63) << 5;
  const int tid = threadIdx.x;
  const int wv = tid >> 6, lane = tid & 63;
  const int j = tid & 15;
  const int ca = (tid >> 4) & 15;
  const int l0 = c * CLEN;
  const size_t base = (size_t)(b * SEQ + l0);

  {
    int row = wv * 16 + (lane >> 3);
    int col = (lane & 7) << 2;
#pragma unroll
    for (int k = 0; k < 2; ++k) {
      gload_lds16f(xs  + (base + row + k * 8) * DI + dbase + col, &lds[(wv * 16 + k * 8) * 32]);
      gload_lds16f(dts + (base + row + k * 8) * DI + dbase + col, &lds[2048 + (wv * 16 + k * 8) * 32]);
    }
#pragma unroll
    for (int k = 0; k < 2; ++k) {
      int seg = wv * 2 + k;
      gload_lds16f(bcb + base * DS + seg * 256 + lane * 4, &lds[4096 + seg * 256]);
    }
  }

  const int dA = dbase + 2 * ca;
  v2f Ar, Ai;
  Ar.x = -0.5f * expf(A_log[dA * DS + j]);
  Ar.y = -0.5f * expf(A_log[(dA + 1) * DS + j]);
  Ai.x = -0.5f * expf(A_log[dA * DS + j + 16]);
  Ai.y = -0.5f * expf(A_log[(dA + 1) * DS + j + 16]);
  const float fr = rope[j];
  float sn, cs, sF, cF;
  sincosf((float)l0 * fr, &sn, &cs);
  sincosf(fr, &sF, &cF);
  __syncthreads();

  v2f p00 = {1.f, 1.f}, p01 = {0.f, 0.f}, p10 = {0.f, 0.f}, p11 = {1.f, 1.f};
  v2f ur = {0.f, 0.f}, ui = {0.f, 0.f};

#pragma unroll 4
  for (int tt = 0; tt < CLEN; ++tt) {
    const int ro = tt * 32;
    v2f xin = *(const v2f*)&lds[ro + 2 * ca];
    v2f dtd = *(const v2f*)&lds[2048 + ro + 2 * ca];
    float Br = lds[4096 + ro + j];
    float Bi = lds[4096 + ro + j + 16];
    v2f hr = dtd * Ar, hi = dtd * Ai;
    v2f invr, invi;
    invr.x = __builtin_amdgcn_rcpf(1.f - hr.x);
    invr.y = __builtin_amdgcn_rcpf(1.f - hr.y);
    invi.x = __builtin_amdgcn_rcpf(1.f - hi.x);
    invi.y = __builtin_amdgcn_rcpf(1.f - hi.y);
    v2f Abr = 2.f * invr - 1.f;
    v2f Abi = 2.f * invi - 1.f;
    v2f dx = dtd * xin;
    v2f bxr = dx * invr * Br;
    v2f bxi = dx * invi * Bi;
    v2f tr = Abr * ur + bxr;
    v2f ti = Abi * ui + bxi;
    ur = tr * cs - ti * sn;
    ui = tr * sn + ti * cs;
    v2f q00 = Abr * p00, q01 = Abr * p01;
    v2f q10 = Abi * p10, q11 = Abi * p11;
    p00 = q00 * cs - q10 * sn; p10 = q00 * sn + q10 * cs;
    p01 = q01 * cs - q11 * sn; p11 = q01 * sn + q11 * cs;
    float nc = fmaf(cs, cF, -sn * sF);
    float ns = fmaf(sn, cF,  cs * sF);
    cs = nc; sn = ns;
  }
  const int pc = (b * 1024 + (dbase >> 1) + ca) * 16 + j;
  float2* Pb2 = (float2*)Pbuf;
  Pb2[(c * 6 + 0) * NPAIRH + pc] = make_float2(p00.x, p00.y);
  Pb2[(c * 6 + 1) * NPAIRH + pc] = make_float2(p01.x, p01.y);
  Pb2[(c * 6 + 2) * NPAIRH + pc] = make_float2(p10.x, p10.y);
  Pb2[(c * 6 + 3) * NPAIRH + pc] = make_float2(p11.x, p11.y);
  Pb2[(c * 6 + 4) * NPAIRH + pc] = make_float2(ur.x, ur.y);
  Pb2[(c * 6 + 5) * NPAIRH + pc] = make_float2(ui.x, ui.y);
}

__global__ __launch_bounds__(256) void scan_p3(const float* __restrict__ xs,
                                               const float* __restrict__ dts,
                                               const float* __restrict__ bcb,
                                               const float* __restrict__ A_log,
                                               const float* __restrict__ rope,
                                               const float* __restrict__ Pbuf,
                                               float* __restrict__ y,
                                               float* __restrict__ fstate) {
  __shared__ __align__(16) float lds[8192];
  const int blk = blockIdx.x;           // 1024
  const int c = blk >> 7;
  const int sub = blk & 127;
  const int b = sub >> 6;
  const int dbase = (sub & 63) << 5;
  const int tid = threadIdx.x;
  const int wv = tid >> 6, lane = tid & 63;
  const int j = tid & 15;
  const int ca = (tid >> 4) & 15;
  const int l0 = c * CLEN;
  const size_t base = (size_t)(b * SEQ + l0);

  {
    int row = wv * 16 + (lane >> 3);
    int col = (lane & 7) << 2;
#pragma unroll
    for (int k = 0; k < 2; ++k) {
      gload_lds16f(xs  + (base + row + k * 8) * DI + dbase + col, &lds[(wv * 16 + k * 8) * 32]);
      gload_lds16f(dts + (base + row + k * 8) * DI + dbase + col, &lds[2048 + (wv * 16 + k * 8) * 32]);
    }
#pragma unroll
    for (int k = 0; k < 2; ++k) {
      int seg = wv * 2 + k;
      gload_lds16f(bcb + base * DS + seg * 256 + lane * 4, &lds[4096 + seg * 256]);
      gload_lds16f(bcb + (size_t)TOK * DS + base * DS + seg * 256 + lane * 4, &lds[6144 + seg * 256]);
    }
  }

  const int dA = dbase + 2 * ca;
  v2f Ar, Ai;
  Ar.x = -0.5f * expf(A_log[dA * DS + j]);
  Ar.y = -0.5f * expf(A_log[(dA + 1) * DS + j]);
  Ai.x = -0.5f * expf(A_log[dA * DS + j + 16]);
  Ai.y = -0.5f * expf(A_log[(dA + 1) * DS + j + 16]);
  const float fr = rope[j];
  float sn, cs, sF, cF;
  sincosf((float)l0 * fr, &sn, &cs);
  sincosf(fr, &sF, &cF);

  // compose entry state from prior chunks (overlaps the staging drain)
  const int pc = (b * 1024 + (dbase >> 1) + ca) * 16 + j;
  const float2* Pb2 = (const float2*)Pbuf;
  v2f sr = {0.f, 0.f}, si = {0.f, 0.f};
  for (int k = 0; k < c; ++k) {
    float2 f;
    f = Pb2[(k * 6 + 0) * NPAIRH + pc]; v2f p00 = {f.x, f.y};
    f = Pb2[(k * 6 + 1) * NPAIRH + pc]; v2f p01 = {f.x, f.y};
    f = Pb2[(k * 6 + 2) * NPAIRH + pc]; v2f p10 = {f.x, f.y};
    f = Pb2[(k * 6 + 3) * NPAIRH + pc]; v2f p11 = {f.x, f.y};
    f = Pb2[(k * 6 + 4) * NPAIRH + pc]; v2f ur  = {f.x, f.y};
    f = Pb2[(k * 6 + 5) * NPAIRH + pc]; v2f ui  = {f.x, f.y};
    v2f nr = p00 * sr + p01 * si + ur;
    v2f ni = p10 * sr + p11 * si + ui;
    sr = nr; si = ni;
  }
  __syncthreads();

  float* yp = y + base * DI + dA;

#pragma unroll 4
  for (int tt = 0; tt < CLEN; ++tt) {
    const int ro = tt * 32;
    v2f xin = *(const v2f*)&lds[ro + 2 * ca];
    v2f dtd = *(const v2f*)&lds[2048 + ro + 2 * ca];
    float Br = lds[4096 + ro + j];
    float Bi = lds[4096 + ro + j + 16];
    float Cr = lds[6144 + ro + j];
    float Ci = lds[6144 + ro + j + 16];
    v2f hr = dtd * Ar, hi = dtd * Ai;
    v2f invr, invi;
    invr.x = __builtin_amdgcn_rcpf(1.f - hr.x);
    invr.y = __builtin_amdgcn_rcpf(1.f - hr.y);
    invi.x = __builtin_amdgcn_rcpf(1.f - hi.x);
    invi.y = __builtin_amdgcn_rcpf(1.f - hi.y);
    v2f Abr = 2.f * invr - 1.f;
    v2f Abi = 2.f * invi - 1.f;
    v2f dx = dtd * xin;
    v2f bxr = dx * invr * Br;
    v2f bxi = dx * invi * Bi;
    v2f tr = Abr * sr + bxr;
    v2f ti = Abi * si + bxi;
    sr = tr * cs - ti * sn;
    si = tr * sn + ti * cs;
    v2f p = sr * Cr + si * Ci;
    float pA = row16_sum(p.x);
    float pB = row16_sum(p.y);
    if (j == 0) *(float2*)&yp[tt * DI] = make_float2(pA, pB);
    float nc = fmaf(cs, cF, -sn * sF);
    float ns = fmaf(sn, cF,  cs * sF);
    cs = nc; sn = ns;
  }
  if (c == NCH - 1) {
    fstate[((size_t)b * DI + dA) * DS + j]          = sr.x;
    fstate[((size_t)b * DI + dA) * DS + j + 16]     = si.x;
    fstate[((size_t)b * DI + dA + 1) * DS + j]      = sr.y;
    fstate[((size_t)b * DI + dA + 1) * DS + j + 16] = si.y;
  }
}

// ---------------- gate (y * silu(z)) + LayerNorm, bf16 output ----------------
__global__ __launch_bounds__(256) void gate_ln(const float* __restrict__ y,
                                               const float* __restrict__ zb,
                                               const float* __restrict__ lw,
                                               const float* __restrict__ lb,
                                               unsigned short* __restrict__ o) {
  int tok = blockIdx.x;
  int t = threadIdx.x;
  float g[8];
  float sum = 0.f, sq = 0.f;
#pragma unroll
  for (int i = 0; i < 8; ++i) {
    int dd = t + i * 256;
    float yv = y[(size_t)tok * DI + dd];
    float zv = zb[(size_t)tok * DI + dd];
    float sg = zv / (1.f + __expf(-zv));
    float v = yv * sg;
    g[i] = v; sum += v; sq += v * v;
  }
#pragma unroll
  for (int off = 32; off; off >>= 1) { sum += __shfl_xor(sum, off); sq += __shfl_xor(sq, off); }
  __shared__ float rs[4], rq[4];
  int w = t >> 6;
  if ((t & 63) == 0) { rs[w] = sum; rq[w] = sq; }
  __syncthreads();
  sum = rs[0] + rs[1] + rs[2] + rs[3];
  sq  = rq[0] + rq[1] + rq[2] + rq[3];
  float mu = sum * (1.f / DI);
  float var = sq * (1.f / DI) - mu * mu;
  float rstd = rsqrtf(var + 1e-5f);
#pragma unroll
  for (int i = 0; i < 8; ++i) {
    int dd = t + i * 256;
    o[(size_t)tok * DI + dd] = f2bf((g[i] - mu) * rstd * lw[dd] + lb[dd]);
  }
}

// ---------------- launch ----------------
extern "C" void kernel_launch(void* const* d_in, const int* in_sizes, int n_in,
                              void* d_out, int out_size, void* d_ws, size_t ws_size,
                              hipStream_t stream) {
  const float* x       = (const float*)d_in[0];
  const float* W_in    = (const float*)d_in[1];
  const float* A_log   = (const float*)d_in[2];
  const float* W_B     = (const float*)d_in[3];
  const float* W_C     = (const float*)d_in[4];
  const float* W_dt    = (const float*)d_in[5];
  const float* b_dt    = (const float*)d_in[6];
  const float* dt_bias = (const float*)d_in[7];
  const float* rope    = (const float*)d_in[8];
  const float* ln_w    = (const float*)d_in[9];
  const float* ln_b    = (const float*)d_in[10];
  const float* W_out   = (const float*)d_in[11];
  float* out = (float*)d_out;
  float* ws = (float*)d_ws;

  // workspace layout (float offsets); overlays noted
  float* xs   = ws;                                   // [0, 2097152)
  float* zb   = ws + 2097152;                         // [2097152, 4194304)
  float* dts  = ws + 4194304;                         // [4194304, 6291456)
  float* bcb  = ws + 6291456;                         // [6291456, 6356992)
  unsigned short* wob  = (unsigned short*)(ws + 6356992);  // 2M bf16   [.., 7405568)
  unsigned short* xb   = (unsigned short*)(ws + 7405568);  // 1M bf16   [.., 7929856)
  unsigned short* wcat = (unsigned short*)(ws + 7929856);  // 6.42M bf16 [.., 11141120)
  float* Pbuf = ws + 7929856;                         // alias wcat (dead after fused GEMM)
  float* yb   = ws + 11141120;                        // 2097152 f  [.., 13238272)
  unsigned short* lnb = (unsigned short*)(ws + 13238272);  // 2M bf16 [.., 14286848)
  float* Pk   = ws;                                   // split-K partials, alias xs (dead after p3)
  float* fstate = out + (size_t)TOK * DM;

  // 1) fused bf16 casts (x, W_in, W_dt, W_B, W_C, W_out)
  fused_cast<<<4640, 256, 0, stream>>>(x, W_in, W_dt, W_B, W_C, W_out, xb, wcat, wob);
  // 2) fused input GEMM, 64x64 tiles, BK=64, 1568 blocks, XCD-swizzled
  gemm_mfma<16, 98, 1, true><<<16 * 98, 256, 0, stream>>>(
      xb, wcat, DM, xs, zb, dts, bcb, b_dt, dt_bias, nullptr, 0);
  // 3) chunked scan: p1 (local P,u; chunk 7 skipped) then p3 (compose entry inline + re-scan)
  scan_p1<<<(NCH - 1) * 128, 256, 0, stream>>>(xs, dts, bcb, A_log, rope, Pbuf);
  scan_p3<<<NCH * 128, 256, 0, stream>>>(xs, dts, bcb, A_log, rope, Pbuf, yb, fstate);
  // 4) gate + LN (bf16 out)
  gate_ln<<<TOK, 256, 0, stream>>>(yb, zb, ln_w, ln_b, lnb);
  // 5) out = ln @ W_out^T, split-K=2 (512 blocks), partials into Pk (dead xs region)
  gemm_mfma<16, 16, 2, false><<<16 * 16 * 2, 256, 0, stream>>>(
      lnb, wob, DI, nullptr, nullptr, nullptr, nullptr, nullptr, nullptr, Pk, DM);
  // 6) out = Pk0 + Pk1
  addk<<<(TOK * DM) / 1024, 256, 0, stream>>>(Pk, Pk + (size_t)TOK * DM, out);
}

// Round 12
// 209.084 us; speedup vs baseline: 1.8647x; 1.0326x over previous
//
#include <hip/hip_runtime.h>
#include <math.h>

// Problem constants
#define B_SZ 2
#define SEQ 512
#define DM 1024
#define DI 2048
#define DS 32
#define TOK (B_SZ*SEQ)        // 1024
#define NCH 8                 // scan chunks
#define CLEN (SEQ/NCH)        // 64
#define NPAIRH 32768          // (b, d-pair, j) chain-pair ids

// fused weight layout (rows of K=1024, bf16):
//   [0,4096) W_in | [4096,6144) W_dt | [6144,6176) W_B | [6176,6208) W_C | [6208,6272) pad
#define NFUSED 6272

typedef float v2f __attribute__((ext_vector_type(2)));

__device__ __forceinline__ unsigned short f2bf(float f) {
  unsigned int u = __builtin_bit_cast(unsigned int, f);
  unsigned int r = u + 0x7fffu + ((u >> 16) & 1u);   // RNE (inputs finite)
  return (unsigned short)(r >> 16);
}

// DPP row-rotate add: sums over the 16-lane row with 4 VALU ops (no LDS pipe).
template<int CTRL>
__device__ __forceinline__ float row_ror_add(float x) {
  int s = __builtin_amdgcn_update_dpp(0, __builtin_bit_cast(int, x), CTRL, 0xf, 0xf, false);
  return x + __builtin_bit_cast(float, s);
}
__device__ __forceinline__ float row16_sum(float v) {
  v = row_ror_add<0x121>(v);
  v = row_ror_add<0x122>(v);
  v = row_ror_add<0x124>(v);
  v = row_ror_add<0x128>(v);
  return v;
}

// ---------------- fused fp32 -> bf16 cast of all 6 tensors, 8 elems/thread ----------------
__global__ __launch_bounds__(256) void fused_cast(const float* __restrict__ x,
                                                  const float* __restrict__ W_in,
                                                  const float* __restrict__ W_dt,
                                                  const float* __restrict__ W_B,
                                                  const float* __restrict__ W_C,
                                                  const float* __restrict__ W_out,
                                                  unsigned short* __restrict__ xb,
                                                  unsigned short* __restrict__ wcat,
                                                  unsigned short* __restrict__ wob) {
  int g = blockIdx.x * 256 + threadIdx.x;
  const float* s; unsigned short* dd; int off;
  if      (g <  131072) { s = x;     dd = xb;             off = 0; }
  else if (g <  655360) { s = W_in;  dd = wcat;           off = 131072; }
  else if (g <  917504) { s = W_dt;  dd = wcat + 4194304; off = 655360; }
  else if (g <  921600) { s = W_B;   dd = wcat + 6291456; off = 917504; }
  else if (g <  925696) { s = W_C;   dd = wcat + 6324224; off = 921600; }
  else if (g < 1187840) { s = W_out; dd = wob;            off = 925696; }
  else return;
  int i = g - off;
  float4 a = ((const float4*)s)[i * 2];
  float4 b = ((const float4*)s)[i * 2 + 1];
  union { unsigned short us[8]; uint4 v; } o;
  o.us[0] = f2bf(a.x); o.us[1] = f2bf(a.y); o.us[2] = f2bf(a.z); o.us[3] = f2bf(a.w);
  o.us[4] = f2bf(b.x); o.us[5] = f2bf(b.y); o.us[6] = f2bf(b.z); o.us[7] = f2bf(b.w);
  ((uint4*)dd)[i] = o.v;
}

// ---------------- bf16 MFMA GEMM (C = A * B^T), 64x64 tile, BK=64, XOR-swizzled LDS ----------
typedef __attribute__((ext_vector_type(8))) short  frag8;
typedef __attribute__((ext_vector_type(4))) float  facc4;

__device__ __forceinline__ void gload_lds16(const unsigned short* g, unsigned short* l) {
  __builtin_amdgcn_global_load_lds((const __attribute__((address_space(1))) unsigned int*)g,
                                   (__attribute__((address_space(3))) unsigned int*)l, 16, 0, 0);
}
__device__ __forceinline__ void gload_lds16f(const float* g, float* l) {
  __builtin_amdgcn_global_load_lds((const __attribute__((address_space(1))) unsigned int*)g,
                                   (__attribute__((address_space(3))) unsigned int*)l, 16, 0, 0);
}

__device__ __forceinline__ float softplus_fast(float v) {
  return fmaxf(v, 0.f) + __logf(1.f + __expf(-fabsf(v)));
}

// LDS swizzle: row r's k-segment s (8 bf16 = 16 B) lives at segment s^(r&7).
// Staging pays nothing (source-addr permute); reads hit all 8 bank-quads -> conflict-free.
template<int MT, int NT, int KSP, bool ROUTE>
__global__ __launch_bounds__(256) void gemm_mfma(const unsigned short* __restrict__ A,
                                                 const unsigned short* __restrict__ Bw,
                                                 int K,
                                                 float* __restrict__ o_xs,
                                                 float* __restrict__ o_zb,
                                                 float* __restrict__ o_dts,
                                                 float* __restrict__ o_bcb,
                                                 const float* __restrict__ b_dt,
                                                 const float* __restrict__ dt_bias,
                                                 float* __restrict__ o_c, int ldc) {
  __shared__ __align__(16) unsigned short As[64 * 64];   // 8 KB
  __shared__ __align__(16) unsigned short Bs[64 * 64];   // 8 KB
  const int tid = threadIdx.x;
  const int w = tid >> 6, lane = tid & 63;
  const int wm = w >> 1, wn = w & 1;
  const int bid = blockIdx.x;
  const int Wk = (bid & 7) * ((int)gridDim.x >> 3) + (bid >> 3);
  const int ks = Wk / (MT * NT);
  const int rem = Wk % (MT * NT);
  const int m0 = (rem % MT) * 64;
  const int n0 = (rem / MT) * 64;
  const int kLen = K / KSP, kBeg = ks * kLen;
  const int r = lane & 15, q = lane >> 4;
  const int srow = lane >> 3;                         // staging row-in-chunk (0..7)
  const int scol = ((lane & 7) ^ (srow & 7)) * 8;     // XOR-swizzled source k-seg
  facc4 acc[2][2] = {};
  const unsigned short* Ag = A + (size_t)m0 * K + kBeg;
  const unsigned short* Bg = Bw + (size_t)n0 * K + kBeg;

  for (int k0 = 0; k0 < kLen; k0 += 64) {
#pragma unroll
    for (int k = 0; k < 2; ++k) {
      int ch = w * 2 + k;                // 8 chunks of 8 rows x 64 k (1 KB)
      gload_lds16(Ag + (size_t)(ch * 8 + srow) * K + k0 + scol, &As[ch * 512]);
      gload_lds16(Bg + (size_t)(ch * 8 + srow) * K + k0 + scol, &Bs[ch * 512]);
    }
    __syncthreads();                     // drains global_load_lds
#pragma unroll
    for (int kk = 0; kk < 2; ++kk) {
      frag8 af[2], bf[2];
      const int sw = ((kk * 4 + q) ^ (r & 7)) * 8;    // swizzled seg offset (row&7 == r&7)
#pragma unroll
      for (int i = 0; i < 2; ++i)
        af[i] = *(const frag8*)&As[(wm * 32 + i * 16 + r) * 64 + sw];
#pragma unroll
      for (int jj = 0; jj < 2; ++jj)
        bf[jj] = *(const frag8*)&Bs[(wn * 32 + jj * 16 + r) * 64 + sw];
#pragma unroll
      for (int i = 0; i < 2; ++i)
#pragma unroll
        for (int jj = 0; jj < 2; ++jj)
          acc[i][jj] = __builtin_amdgcn_mfma_f32_16x16x32_bf16(af[i], bf[jj], acc[i][jj], 0, 0, 0);
    }
    __syncthreads();
  }

#pragma unroll
  for (int i = 0; i < 2; ++i) {
#pragma unroll
    for (int jj = 0; jj < 2; ++jj) {
      int n = n0 + wn * 32 + jj * 16 + r;
      int mb = m0 + wm * 32 + i * 16 + q * 4;
      if (ROUTE) {
        if (n < 2048) {
#pragma unroll
          for (int rg = 0; rg < 4; ++rg)
            o_xs[(size_t)(mb + rg) * DI + n] = acc[i][jj][rg];
        } else if (n < 4096) {
#pragma unroll
          for (int rg = 0; rg < 4; ++rg)
            o_zb[(size_t)(mb + rg) * DI + (n - 2048)] = acc[i][jj][rg];
        } else if (n < 6144) {
          int d = n - 4096;
          float bias = b_dt[d] + dt_bias[d];
#pragma unroll
          for (int rg = 0; rg < 4; ++rg)
            o_dts[(size_t)(mb + rg) * DI + d] = softplus_fast(acc[i][jj][rg] + bias);
        } else if (n < 6176) {
#pragma unroll
          for (int rg = 0; rg < 4; ++rg)
            o_bcb[(size_t)(mb + rg) * DS + (n - 6144)] = acc[i][jj][rg];
        } else if (n < 6208) {
#pragma unroll
          for (int rg = 0; rg < 4; ++rg)
            o_bcb[(size_t)TOK * DS + (size_t)(mb + rg) * DS + (n - 6176)] = acc[i][jj][rg];
        }
      } else {
        float* oc = o_c + (size_t)ks * (MT * 64) * ldc;
#pragma unroll
        for (int rg = 0; rg < 4; ++rg)
          oc[(size_t)(mb + rg) * ldc + n] = acc[i][jj][rg];
      }
    }
  }
}

// ---------------- split-K reduction: out = P0 + P1 (float4) ----------------
__global__ __launch_bounds__(256) void addk(const float* __restrict__ p0,
                                            const float* __restrict__ p1,
                                            float* __restrict__ o) {
  int i = blockIdx.x * 256 + threadIdx.x;
  float4 a = ((const float4*)p0)[i];
  float4 b = ((const float4*)p1)[i];
  ((float4*)o)[i] = make_float4(a.x + b.x, a.y + b.y, a.z + b.z, a.w + b.w);
}

// ---------------- chunked scan: LDS-staged chunk, v2f packed chains (d, d+1) ----------------
__global__ __launch_bounds__(256) void scan_p1(const float* __restrict__ xs,
                                               const float* __restrict__ dts,
                                               const float* __restrict__ bcb,
                                               const float* __restrict__ A_log,
                                               const float* __restrict__ rope,
                                               float* __restrict__ Pbuf) {
  __shared__ __align__(16) float lds[6144];
  const int blk = blockIdx.x;           // 896 = 7 chunks x 128 (chunk 7's P,u never consumed)
  const int c = blk >> 7;
  const int sub = blk & 127;
  const int b = sub >> 6;
  const int dbase = (sub & 63) << 5;
  const int tid = threadIdx.x;
  const int wv = tid >> 6, lane = tid & 63;
  const int j = tid & 15;
  const int ca = (tid >> 4) & 15;
  const int l0 = c * CLEN;
  const size_t base = (size_t)(b * SEQ + l0);

  {
    int row = wv * 16 + (lane >> 3);
    int col = (lane & 7) << 2;
#pragma unroll
    for (int k = 0; k < 2; ++k) {
      gload_lds16f(xs  + (base + row + k * 8) * DI + dbase + col, &lds[(wv * 16 + k * 8) * 32]);
      gload_lds16f(dts + (base + row + k * 8) * DI + dbase + col, &lds[2048 + (wv * 16 + k * 8) * 32]);
    }
#pragma unroll
    for (int k = 0; k < 2; ++k) {
      int seg = wv * 2 + k;
      gload_lds16f(bcb + base * DS + seg * 256 + lane * 4, &lds[4096 + seg * 256]);
    }
  }

  const int dA = dbase + 2 * ca;
  v2f Ar, Ai;
  Ar.x = -0.5f * expf(A_log[dA * DS + j]);
  Ar.y = -0.5f * expf(A_log[(dA + 1) * DS + j]);
  Ai.x = -0.5f * expf(A_log[dA * DS + j + 16]);
  Ai.y = -0.5f * expf(A_log[(dA + 1) * DS + j + 16]);
  const float fr = rope[j];
  float sn, cs, sF, cF;
  sincosf((float)l0 * fr, &sn, &cs);
  sincosf(fr, &sF, &cF);
  __syncthreads();

  v2f p00 = {1.f, 1.f}, p01 = {0.f, 0.f}, p10 = {0.f, 0.f}, p11 = {1.f, 1.f};
  v2f ur = {0.f, 0.f}, ui = {0.f, 0.f};

#pragma unroll 4
  for (int tt = 0; tt < CLEN; ++tt) {
    const int ro = tt * 32;
    v2f xin = *(const v2f*)&lds[ro + 2 * ca];
    v2f dtd = *(const v2f*)&lds[2048 + ro + 2 * ca];
    float Br = lds[4096 + ro + j];
    float Bi = lds[4096 + ro + j + 16];
    v2f hr = dtd * Ar, hi = dtd * Ai;
    v2f invr, invi;
    invr.x = __builtin_amdgcn_rcpf(1.f - hr.x);
    invr.y = __builtin_amdgcn_rcpf(1.f - hr.y);
    invi.x = __builtin_amdgcn_rcpf(1.f - hi.x);
    invi.y = __builtin_amdgcn_rcpf(1.f - hi.y);
    v2f Abr = 2.f * invr - 1.f;
    v2f Abi = 2.f * invi - 1.f;
    v2f dx = dtd * xin;
    v2f bxr = dx * invr * Br;
    v2f bxi = dx * invi * Bi;
    v2f tr = Abr * ur + bxr;
    v2f ti = Abi * ui + bxi;
    ur = tr * cs - ti * sn;
    ui = tr * sn + ti * cs;
    v2f q00 = Abr * p00, q01 = Abr * p01;
    v2f q10 = Abi * p10, q11 = Abi * p11;
    p00 = q00 * cs - q10 * sn; p10 = q00 * sn + q10 * cs;
    p01 = q01 * cs - q11 * sn; p11 = q01 * sn + q11 * cs;
    float nc = fmaf(cs, cF, -sn * sF);
    float ns = fmaf(sn, cF,  cs * sF);
    cs = nc; sn = ns;
  }
  const int pc = (b * 1024 + (dbase >> 1) + ca) * 16 + j;
  float2* Pb2 = (float2*)Pbuf;
  Pb2[(c * 6 + 0) * NPAIRH + pc] = make_float2(p00.x, p00.y);
  Pb2[(c * 6 + 1) * NPAIRH + pc] = make_float2(p01.x, p01.y);
  Pb2[(c * 6 + 2) * NPAIRH + pc] = make_float2(p10.x, p10.y);
  Pb2[(c * 6 + 3) * NPAIRH + pc] = make_float2(p11.x, p11.y);
  Pb2[(c * 6 + 4) * NPAIRH + pc] = make_float2(ur.x, ur.y);
  Pb2[(c * 6 + 5) * NPAIRH + pc] = make_float2(ui.x, ui.y);
}

__global__ __launch_bounds__(256) void scan_p3(const float* __restrict__ xs,
                                               const float* __restrict__ dts,
                                               const float* __restrict__ bcb,
                                               const float* __restrict__ A_log,
                                               const float* __restrict__ rope,
                                               const float* __restrict__ Pbuf,
                                               float* __restrict__ y,
                                               float* __restrict__ fstate) {
  __shared__ __align__(16) float lds[8192];
  const int blk = blockIdx.x;           // 1024
  const int c = blk >> 7;
  const int sub = blk & 127;
  const int b = sub >> 6;
  const int dbase = (sub & 63) << 5;
  const int tid = threadIdx.x;
  const int wv = tid >> 6, lane = tid & 63;
  const int j = tid & 15;
  const int ca = (tid >> 4) & 15;
  const int l0 = c * CLEN;
  const size_t base = (size_t)(b * SEQ + l0);

  {
    int row = wv * 16 + (lane >> 3);
    int col = (lane & 7) << 2;
#pragma unroll
    for (int k = 0; k < 2; ++k) {
      gload_lds16f(xs  + (base + row + k * 8) * DI + dbase + col, &lds[(wv * 16 + k * 8) * 32]);
      gload_lds16f(dts + (base + row + k * 8) * DI + dbase + col, &lds[2048 + (wv * 16 + k * 8) * 32]);
    }
#pragma unroll
    for (int k = 0; k < 2; ++k) {
      int seg = wv * 2 + k;
      gload_lds16f(bcb + base * DS + seg * 256 + lane * 4, &lds[4096 + seg * 256]);
      gload_lds16f(bcb + (size_t)TOK * DS + base * DS + seg * 256 + lane * 4, &lds[6144 + seg * 256]);
    }
  }

  const int dA = dbase + 2 * ca;
  v2f Ar, Ai;
  Ar.x = -0.5f * expf(A_log[dA * DS + j]);
  Ar.y = -0.5f * expf(A_log[(dA + 1) * DS + j]);
  Ai.x = -0.5f * expf(A_log[dA * DS + j + 16]);
  Ai.y = -0.5f * expf(A_log[(dA + 1) * DS + j + 16]);
  const float fr = rope[j];
  float sn, cs, sF, cF;
  sincosf((float)l0 * fr, &sn, &cs);
  sincosf(fr, &sF, &cF);

  // compose entry state from prior chunks (overlaps the staging drain)
  const int pc = (b * 1024 + (dbase >> 1) + ca) * 16 + j;
  const float2* Pb2 = (const float2*)Pbuf;
  v2f sr = {0.f, 0.f}, si = {0.f, 0.f};
  for (int k = 0; k < c; ++k) {
    float2 f;
    f = Pb2[(k * 6 + 0) * NPAIRH + pc]; v2f p00 = {f.x, f.y};
    f = Pb2[(k * 6 + 1) * NPAIRH + pc]; v2f p01 = {f.x, f.y};
    f = Pb2[(k * 6 + 2) * NPAIRH + pc]; v2f p10 = {f.x, f.y};
    f = Pb2[(k * 6 + 3) * NPAIRH + pc]; v2f p11 = {f.x, f.y};
    f = Pb2[(k * 6 + 4) * NPAIRH + pc]; v2f ur  = {f.x, f.y};
    f = Pb2[(k * 6 + 5) * NPAIRH + pc]; v2f ui  = {f.x, f.y};
    v2f nr = p00 * sr + p01 * si + ur;
    v2f ni = p10 * sr + p11 * si + ui;
    sr = nr; si = ni;
  }
  __syncthreads();

  float* yp = y + base * DI + dA;

#pragma unroll 4
  for (int tt = 0; tt < CLEN; ++tt) {
    const int ro = tt * 32;
    v2f xin = *(const v2f*)&lds[ro + 2 * ca];
    v2f dtd = *(const v2f*)&lds[2048 + ro + 2 * ca];
    float Br = lds[4096 + ro + j];
    float Bi = lds[4096 + ro + j + 16];
    float Cr = lds[6144 + ro + j];
    float Ci = lds[6144 + ro + j + 16];
    v2f hr = dtd * Ar, hi = dtd * Ai;
    v2f invr, invi;
    invr.x = __builtin_amdgcn_rcpf(1.f - hr.x);
    invr.y = __builtin_amdgcn_rcpf(1.f - hr.y);
    invi.x = __builtin_amdgcn_rcpf(1.f - hi.x);
    invi.y = __builtin_amdgcn_rcpf(1.f - hi.y);
    v2f Abr = 2.f * invr - 1.f;
    v2f Abi = 2.f * invi - 1.f;
    v2f dx = dtd * xin;
    v2f bxr = dx * invr * Br;
    v2f bxi = dx * invi * Bi;
    v2f tr = Abr * sr + bxr;
    v2f ti = Abi * si + bxi;
    sr = tr * cs - ti * sn;
    si = tr * sn + ti * cs;
    v2f p = sr * Cr + si * Ci;
    float pA = row16_sum(p.x);
    float pB = row16_sum(p.y);
    if (j == 0) *(float2*)&yp[tt * DI] = make_float2(pA, pB);
    float nc = fmaf(cs, cF, -sn * sF);
    float ns = fmaf(sn, cF,  cs * sF);
    cs = nc; sn = ns;
  }
  if (c == NCH - 1) {
    fstate[((size_t)b * DI + dA) * DS + j]          = sr.x;
    fstate[((size_t)b * DI + dA) * DS + j + 16]     = si.x;
    fstate[((size_t)b * DI + dA + 1) * DS + j]      = sr.y;
    fstate[((size_t)b * DI + dA + 1) * DS + j + 16] = si.y;
  }
}

// ---------------- gate (y * silu(z)) + LayerNorm, bf16 output ----------------
__global__ __launch_bounds__(256) void gate_ln(const float* __restrict__ y,
                                               const float* __restrict__ zb,
                                               const float* __restrict__ lw,
                                               const float* __restrict__ lb,
                                               unsigned short* __restrict__ o) {
  int tok = blockIdx.x;
  int t = threadIdx.x;
  float g[8];
  float sum = 0.f, sq = 0.f;
#pragma unroll
  for (int i = 0; i < 8; ++i) {
    int dd = t + i * 256;
    float yv = y[(size_t)tok * DI + dd];
    float zv = zb[(size_t)tok * DI + dd];
    float sg = zv / (1.f + __expf(-zv));
    float v = yv * sg;
    g[i] = v; sum += v; sq += v * v;
  }
#pragma unroll
  for (int off = 32; off; off >>= 1) { sum += __shfl_xor(sum, off); sq += __shfl_xor(sq, off); }
  __shared__ float rs[4], rq[4];
  int w = t >> 6;
  if ((t & 63) == 0) { rs[w] = sum; rq[w] = sq; }
  __syncthreads();
  sum = rs[0] + rs[1] + rs[2] + rs[3];
  sq  = rq[0] + rq[1] + rq[2] + rq[3];
  float mu = sum * (1.f / DI);
  float var = sq * (1.f / DI) - mu * mu;
  float rstd = rsqrtf(var + 1e-5f);
#pragma unroll
  for (int i = 0; i < 8; ++i) {
    int dd = t + i * 256;
    o[(size_t)tok * DI + dd] = f2bf((g[i] - mu) * rstd * lw[dd] + lb[dd]);
  }
}

// ---------------- launch ----------------
extern "C" void kernel_launch(void* const* d_in, const int* in_sizes, int n_in,
                              void* d_out, int out_size, void* d_ws, size_t ws_size,
                              hipStream_t stream) {
  const float* x       = (const float*)d_in[0];
  const float* W_in    = (const float*)d_in[1];
  const float* A_log   = (const float*)d_in[2];
  const float* W_B     = (const float*)d_in[3];
  const float* W_C     = (const float*)d_in[4];
  const float* W_dt    = (const float*)d_in[5];
  const float* b_dt    = (const float*)d_in[6];
  const float* dt_bias = (const float*)d_in[7];
  const float* rope    = (const float*)d_in[8];
  const float* ln_w    = (const float*)d_in[9];
  const float* ln_b    = (const float*)d_in[10];
  const float* W_out   = (const float*)d_in[11];
  float* out = (float*)d_out;
  float* ws = (float*)d_ws;

  // workspace layout (float offsets); overlays noted
  float* xs   = ws;                                   // [0, 2097152)
  float* zb   = ws + 2097152;                         // [2097152, 4194304)
  float* dts  = ws + 4194304;                         // [4194304, 6291456)
  float* bcb  = ws + 6291456;                         // [6291456, 6356992)
  unsigned short* wob  = (unsigned short*)(ws + 6356992);  // 2M bf16   [.., 7405568)
  unsigned short* xb   = (unsigned short*)(ws + 7405568);  // 1M bf16   [.., 7929856)
  unsigned short* wcat = (unsigned short*)(ws + 7929856);  // 6.42M bf16 [.., 11141120)
  float* Pbuf = ws + 7929856;                         // alias wcat (dead after fused GEMM)
  float* yb   = ws + 11141120;                        // 2097152 f  [.., 13238272)
  unsigned short* lnb = (unsigned short*)(ws + 13238272);  // 2M bf16 [.., 14286848)
  float* Pk   = ws;                                   // split-K partials, alias xs (dead after p3)
  float* fstate = out + (size_t)TOK * DM;

  // 1) fused bf16 casts (x, W_in, W_dt, W_B, W_C, W_out)
  fused_cast<<<4640, 256, 0, stream>>>(x, W_in, W_dt, W_B, W_C, W_out, xb, wcat, wob);
  // 2) fused input GEMM, 64x64 tiles, BK=64, swizzled LDS, 1568 blocks, XCD-swizzled
  gemm_mfma<16, 98, 1, true><<<16 * 98, 256, 0, stream>>>(
      xb, wcat, DM, xs, zb, dts, bcb, b_dt, dt_bias, nullptr, 0);
  // 3) chunked scan: p1 (local P,u; chunk 7 skipped) then p3 (compose entry inline + re-scan)
  scan_p1<<<(NCH - 1) * 128, 256, 0, stream>>>(xs, dts, bcb, A_log, rope, Pbuf);
  scan_p3<<<NCH * 128, 256, 0, stream>>>(xs, dts, bcb, A_log, rope, Pbuf, yb, fstate);
  // 4) gate + LN (bf16 out)
  gate_ln<<<TOK, 256, 0, stream>>>(yb, zb, ln_w, ln_b, lnb);
  // 5) out = ln @ W_out^T, split-K=2 (512 blocks), partials into Pk (dead xs region)
  gemm_mfma<16, 16, 2, false><<<16 * 16 * 2, 256, 0, stream>>>(
      lnb, wob, DI, nullptr, nullptr, nullptr, nullptr, nullptr, nullptr, Pk, DM);
  // 6) out = Pk0 + Pk1
  addk<<<(TOK * DM) / 1024, 256, 0, stream>>>(Pk, Pk + (size_t)TOK * DM, out);
}